// Round 10
// baseline (234.625 us; speedup 1.0000x reference)
//
#include <hip/hip_runtime.h>
#include <math.h>

#define RMINF  0.5f
#define LSPAN  5.5f          // RC - RMIN
constexpr int BETA = 12, M1 = 24, M2 = 6;
constexpr int B_ = 4, N_ = 1024, NT_ = 2, MN_ = 128;
constexpr int K_ = NT_ * MN_;        // 256
constexpr int NFEAT = M1 * M2;       // 144
constexpr int HID = 128;
constexpr float PI_F = 3.14159265358979323846f;

// Output layout: Etot(4) | Ei(4096) | Force(4*1024*3) | Virial(36)
constexpr int EI_OFF = B_;                  // 4
constexpr int F_OFF  = B_ + B_ * N_;        // 4100
constexpr int V_OFF  = F_OFF + B_ * N_ * 3; // 16388

constexpr int G_ = 4;                 // source atoms per k3 block
constexpr int NG = B_ * N_ / G_;      // 1024 k3 blocks
constexpr int SL = 8;                 // reduce slices

// Workspace layout (floats); total ~16.9 MB
constexpr size_t WS_FEAT    = 0;                          // 4096*144
constexpr size_t WS_R       = (size_t)B_ * N_ * NFEAT;    // 4096*96
constexpr size_t WS_VIR     = WS_R + (size_t)B_ * N_ * 96;      // 1024*9
constexpr size_t WS_CONTRIB = WS_VIR + (size_t)NG * 9;          // 1024*3072
constexpr size_t WS_PARTIAL = WS_CONTRIB + (size_t)NG * N_ * 3; // 8*4*3072

// NOTE: no occupancy-floor arg on launch_bounds anywhere. (256,4) capped the
// allocator at 64 VGPR -> per-thread arrays spilled to scratch -> ~2 GB HBM
// traffic (rounds 4/6). Round 8 confirmed: VGPR 220, WRITE 12 MB, 104 us.
// Round 9: k2 4-atom blocking -> grid 512 = 2 blocks/CU = latency-bound
// (occ 19.8%, VALU 23%). Round 10: k2 -> 1 n per block, 512 thr (4b x 128c).

// ---------------- K1: embedding forward -> feat, R ----------------
// Algebraic form: M[tk][j][c] = sum_k fc*T_j*sr_c ; R = (c_param . M)/MN.
__global__ __launch_bounds__(256) void k1_embed(
    const int*   __restrict__ list_neigh,
    const int*   __restrict__ type_map,
    const float* __restrict__ imagedr,
    const float* __restrict__ c_param,
    const float* __restrict__ scale,
    float* __restrict__ feat_ws,
    float* __restrict__ R_ws)
{
    __shared__ float c_sh[NT_ * M1 * BETA];   // [tk][f][j] 576
    __shared__ float p_sh[K_][13];            // fc*T_j, padded
    __shared__ float sr_sh[K_][5];
    __shared__ float Mpart[2][96];            // [sub][tk*48 + j*4 + c]
    __shared__ float R_sh[96];

    const int tid = threadIdx.x;
    const int bn = blockIdx.x;
    const int n  = bn % N_;
    const int tn = type_map[n];

    for (int i = tid; i < NT_ * M1 * BETA; i += 256)
        c_sh[i] = c_param[tn * (NT_ * M1 * BETA) + i];

    const int k = tid;
    const int lni = list_neigh[(size_t)bn * K_ + k];
    const float valid = (lni >= 0) ? 1.0f : 0.0f;

    const float4 dr4 = reinterpret_cast<const float4*>(imagedr)[(size_t)bn * K_ + k];
    const float rx = dr4.y, ry = dr4.z, rz = dr4.w;
    const float r  = sqrtf(rx*rx + ry*ry + rz*rz + 1e-12f);
    const float uraw = (r - RMINF) / LSPAN;
    const float u  = fminf(fmaxf(uraw, 0.0f), 1.0f);
    const float fc = 0.5f * (cosf(PI_F * u) + 1.0f) * valid;
    const float x  = 2.0f * (r - RMINF) / LSPAN - 1.0f;

    float T[BETA];
    T[0] = 1.0f; T[1] = x;
#pragma unroll
    for (int j = 2; j < BETA; ++j) T[j] = 2.0f * x * T[j-1] - T[j-2];

    const float inv_r = 1.0f / r;
    sr_sh[k][0] = valid;
    sr_sh[k][1] = valid * rx * inv_r;
    sr_sh[k][2] = valid * ry * inv_r;
    sr_sh[k][3] = valid * rz * inv_r;
#pragma unroll
    for (int j = 0; j < BETA; ++j) p_sh[k][j] = fc * T[j];
    __syncthreads();

    // M partial: 192 threads, each sums 64 neighbors for one (tk,j,c)
    if (tid < 192) {
        const int sub = tid / 96, idx = tid % 96;
        const int tk = idx / 48, rem = idx % 48;
        const int j = rem >> 2, cc = rem & 3;
        const int k0 = tk * 128 + sub * 64;
        float a0 = 0.0f, a1 = 0.0f;
        for (int kk = k0; kk < k0 + 64; kk += 2) {
            a0 = fmaf(p_sh[kk][j],   sr_sh[kk][cc],   a0);
            a1 = fmaf(p_sh[kk+1][j], sr_sh[kk+1][cc], a1);
        }
        Mpart[sub][idx] = a0 + a1;
    }
    __syncthreads();

    // R[f][c] = (1/MN) sum_tk sum_j c[tk][f][j] * M[tk][j][c]
    if (tid < 96) {
        const int f = tid >> 2, cc = tid & 3;
        float acc = 0.0f;
#pragma unroll
        for (int tk = 0; tk < NT_; ++tk) {
#pragma unroll
            for (int j = 0; j < BETA; ++j) {
                const float m = Mpart[0][tk*48 + j*4 + cc] + Mpart[1][tk*48 + j*4 + cc];
                acc = fmaf(c_sh[tk*288 + f*12 + j], m, acc);
            }
        }
        const float v = acc * (1.0f / MN_);
        R_sh[tid] = v;
        R_ws[(size_t)bn * 96 + tid] = v;
    }
    __syncthreads();
    if (tid < NFEAT) {
        const int f = tid / 6, g = tid % 6;
        float acc = 0.0f;
#pragma unroll
        for (int c = 0; c < 4; ++c) acc += R_sh[f * 4 + c] * R_sh[g * 4 + c];
        feat_ws[(size_t)bn * NFEAT + tid] = acc * scale[tid];
    }
}

// ---------------- K2: MLP fwd + bwd, one n per block, 512 thr (4b x 128c) --
__global__ __launch_bounds__(512) void k2_mlp(
    const int*   __restrict__ type_map,
    const float* __restrict__ scale,
    const float* __restrict__ W0,
    const float* __restrict__ b0,
    const float* __restrict__ W1,
    const float* __restrict__ b1,
    const float* __restrict__ W2,
    const float* __restrict__ b2,
    const float* __restrict__ eshift,
    const float* __restrict__ feat_ws,
    float* __restrict__ dfeat_ws,     // may alias feat_ws
    float* __restrict__ out)
{
    __shared__ float feat_sh[4][NFEAT];
    __shared__ float h_sh[4][HID];
    __shared__ float dz1_sh[4][HID];
    __shared__ float dz0_sh[4][HID];
    __shared__ float red[8];          // per-wave Ei partials

    const int tid  = threadIdx.x;
    const int b    = tid >> 7;        // batch 0..3
    const int c    = tid & 127;       // column
    const int lane = tid & 63;
    const int wid  = tid >> 6;        // 0..7 (wave w covers b = w>>1)
    const int n  = blockIdx.x;
    const int tn = type_map[n];

    for (int i = tid; i < 4 * NFEAT; i += 512) {
        const int bb = i / NFEAT, f = i % NFEAT;
        feat_sh[bb][f] = feat_ws[((size_t)bb * N_ + n) * NFEAT + f];
    }
    __syncthreads();

    // layer 0: one column per thread
    float acc = b0[tn * HID + c];
    const float* w0c = W0 + (size_t)tn * NFEAT * HID + c;
#pragma unroll 8
    for (int f = 0; f < NFEAT; ++f)
        acc = fmaf(feat_sh[b][f], w0c[(size_t)f * HID], acc);
    const float h = tanhf(acc);
    h_sh[b][c] = h;
    __syncthreads();

    // layer 1
    float acc1 = b1[tn * HID + c];
    const float* w1c = W1 + (size_t)tn * HID * HID + c;
#pragma unroll 8
    for (int g = 0; g < HID; ++g)
        acc1 = fmaf(h_sh[b][g], w1c[(size_t)g * HID], acc1);
    const float t1 = tanhf(acc1);
    const float w2c = W2[tn * HID + c];
    dz1_sh[b][c] = w2c * (1.0f - t1 * t1);

    // Ei: wave reduce (each wave covers one b's half-columns)
    {
        float v = (t1 + h) * w2c;
#pragma unroll
        for (int m = 32; m >= 1; m >>= 1) v += __shfl_xor(v, m);
        if (lane == 0) red[wid] = v;
    }
    __syncthreads();   // red + dz1_sh ready
    if (tid < 4)
        out[EI_OFF + (size_t)tid * N_ + n] =
            red[tid * 2] + red[tid * 2 + 1] + b2[tn] + eshift[tn];

    // dz0[b][c] = (W2[c] + sum_g W1[c][g] dz1[b][g]) * (1-h^2)
    {
        const float4* w1row = reinterpret_cast<const float4*>(W1 + (size_t)(tn * HID + c) * HID);
        float ar = w2c, arb = 0.0f;
#pragma unroll 4
        for (int g4 = 0; g4 < HID / 4; g4 += 2) {
            const float4 w  = w1row[g4];
            const float4 w2 = w1row[g4 + 1];
            ar  += w.x  * dz1_sh[b][g4*4+0] + w.y  * dz1_sh[b][g4*4+1]
                 + w.z  * dz1_sh[b][g4*4+2] + w.w  * dz1_sh[b][g4*4+3];
            arb += w2.x * dz1_sh[b][g4*4+4] + w2.y * dz1_sh[b][g4*4+5]
                 + w2.z * dz1_sh[b][g4*4+6] + w2.w * dz1_sh[b][g4*4+7];
        }
        dz0_sh[b][c] = (ar + arb) * (1.0f - h * h);
    }
    __syncthreads();

    // dfeat rows f = c (+128 for c<16), per b
    for (int f = c; f < NFEAT; f += HID) {
        const float4* w0row = reinterpret_cast<const float4*>(W0 + (size_t)(tn * NFEAT + f) * HID);
        float ar = 0.0f, arb = 0.0f;
#pragma unroll 4
        for (int h4 = 0; h4 < HID / 4; h4 += 2) {
            const float4 w  = w0row[h4];
            const float4 w2 = w0row[h4 + 1];
            ar  += w.x  * dz0_sh[b][h4*4+0] + w.y  * dz0_sh[b][h4*4+1]
                 + w.z  * dz0_sh[b][h4*4+2] + w.w  * dz0_sh[b][h4*4+3];
            arb += w2.x * dz0_sh[b][h4*4+4] + w2.y * dz0_sh[b][h4*4+5]
                 + w2.z * dz0_sh[b][h4*4+6] + w2.w * dz0_sh[b][h4*4+7];
        }
        dfeat_ws[((size_t)b * N_ + n) * NFEAT + f] = (ar + arb) * scale[f];
    }
}

// ---------------- K3: embedding backward via A = c . dR ------------------
__global__ __launch_bounds__(256) void k3_bwd(
    const int*   __restrict__ list_neigh,
    const int*   __restrict__ type_map,
    const float* __restrict__ imagedr,
    const float* __restrict__ c_param,
    const float* __restrict__ dfeat_ws,
    const float* __restrict__ R_ws,
    float* __restrict__ contrib_ws,
    float* __restrict__ vir_ws)
{
    __shared__ float fcontrib[N_ * 3];      // 12 KB force image
    __shared__ float c_sh[NT_ * M1 * BETA];
    __shared__ float dfeat_sh[NFEAT];
    __shared__ float R_sh[96];
    __shared__ float dR_sh[96];
    __shared__ float A_sh[96];              // [tk][j][c]
    __shared__ float red12[12 * 4];

    const int tid  = threadIdx.x;
    const int lane = tid & 63;
    const int wid  = tid >> 6;
    const int g  = blockIdx.x;
    const int tk = tid >> 7;

    for (int i = tid; i < N_ * 3; i += 256) fcontrib[i] = 0.0f;

    float vv0=0.f,vv1=0.f,vv2=0.f,vv3=0.f,vv4=0.f,vv5=0.f,vv6=0.f,vv7=0.f,vv8=0.f;

    for (int aa = 0; aa < G_; ++aa) {
        const int bn = g * G_ + aa;
        const int n  = bn & (N_ - 1);
        const int tn = type_map[n];

        __syncthreads();
        for (int i = tid; i < NT_ * M1 * BETA; i += 256)
            c_sh[i] = c_param[tn * (NT_ * M1 * BETA) + i];
        if (tid < NFEAT) dfeat_sh[tid] = dfeat_ws[(size_t)bn * NFEAT + tid];
        if (tid < 96)    R_sh[tid]     = R_ws[(size_t)bn * 96 + tid];
        __syncthreads();

        if (tid < 96) {
            const int p = tid >> 2, c = tid & 3;
            float acc = 0.0f;
#pragma unroll
            for (int gg = 0; gg < M2; ++gg) acc += dfeat_sh[p * 6 + gg] * R_sh[gg * 4 + c];
            if (p < M2) {
                for (int f = 0; f < M1; ++f) acc += dfeat_sh[f * 6 + p] * R_sh[f * 4 + c];
            }
            dR_sh[p * 4 + c] = acc * (1.0f / MN_);
        }
        __syncthreads();

        // A[tk][j][c] = sum_f c[tk][f][j] * dR[f][c]
        if (tid < 96) {
            const int atk = tid / 48, rem = tid % 48;
            const int j = rem >> 2, cc = rem & 3;
            float acc = 0.0f;
#pragma unroll
            for (int f = 0; f < M1; ++f)
                acc = fmaf(c_sh[atk*288 + f*12 + j], dR_sh[f*4 + cc], acc);
            A_sh[tid] = acc;
        }
        __syncthreads();

        const int lni = list_neigh[(size_t)bn * K_ + tid];
        const float valid = (lni >= 0) ? 1.0f : 0.0f;
        const float4 dr4 = reinterpret_cast<const float4*>(imagedr)[(size_t)bn * K_ + tid];
        const float rx = dr4.y, ry = dr4.z, rz = dr4.w;
        const float r  = sqrtf(rx*rx + ry*ry + rz*rz + 1e-12f);
        const float uraw = (r - RMINF) / LSPAN;
        const float u  = fminf(fmaxf(uraw, 0.0f), 1.0f);
        const float fc = 0.5f * (cosf(PI_F * u) + 1.0f) * valid;
        const float x  = 2.0f * (r - RMINF) / LSPAN - 1.0f;

        float T[BETA];
        T[0] = 1.0f; T[1] = x;
#pragma unroll
        for (int j = 2; j < BETA; ++j) T[j] = 2.0f * x * T[j-1] - T[j-2];

        const float inv_r = 1.0f / r;
        const float sr0 = valid;
        const float sr1 = valid * rx * inv_r;
        const float sr2 = valid * ry * inv_r;
        const float sr3 = valid * rz * inv_r;

        // single 12-iter contraction: cj_j = A[j].sr ; dfc = T.cj ;
        // tA_c = T.A[:,c] ; dx = cj.T'
        const float* Arow = &A_sh[tk * 48];
        float dfc = 0.0f, dx = 0.0f;
        float tA0 = 0.0f, tA1 = 0.0f, tA2 = 0.0f, tA3 = 0.0f;
        float tpm1 = 1.0f, tpm2 = 0.0f;
#pragma unroll
        for (int j = 0; j < BETA; ++j) {
            const float a0 = Arow[j*4+0], a1 = Arow[j*4+1];
            const float a2 = Arow[j*4+2], a3 = Arow[j*4+3];
            const float cjj = a0*sr0 + a1*sr1 + a2*sr2 + a3*sr3;
            dfc = fmaf(T[j], cjj, dfc);
            tA0 = fmaf(T[j], a0, tA0);
            tA1 = fmaf(T[j], a1, tA1);
            tA2 = fmaf(T[j], a2, tA2);
            tA3 = fmaf(T[j], a3, tA3);
            if (j == 1) {
                dx = cjj;                  // T'_1 = 1
            } else if (j >= 2) {
                const float tp = 2.0f * T[j-1] + 2.0f * x * tpm1 - tpm2;
                dx = fmaf(cjj, tp, dx);
                tpm2 = tpm1; tpm1 = tp;
            }
        }
        const float dsr1 = fc * tA1, dsr2 = fc * tA2, dsr3 = fc * tA3;

        float dfcdr = 0.0f;
        if (uraw > 0.0f && uraw < 1.0f)
            dfcdr = -0.5f * PI_F * sinf(PI_F * u) * valid / LSPAN;
        const float drt = (fc * dx) * (2.0f / LSPAN) + dfc * dfcdr;
        const float Sdot = dsr1 * rx + dsr2 * ry + dsr3 * rz;
        const float common = drt * inv_r - valid * Sdot * inv_r * inv_r * inv_r;
        const float gx = common * rx + valid * dsr1 * inv_r;
        const float gy = common * ry + valid * dsr2 * inv_r;
        const float gz = common * rz + valid * dsr3 * inv_r;

        if (lni >= 0) {
            atomicAdd(&fcontrib[lni * 3 + 0], -gx);
            atomicAdd(&fcontrib[lni * 3 + 1], -gy);
            atomicAdd(&fcontrib[lni * 3 + 2], -gz);
        }

        {
            float s0 = gx, s1 = gy, s2 = gz;
#pragma unroll
            for (int m = 32; m >= 1; m >>= 1) {
                s0 += __shfl_xor(s0, m);
                s1 += __shfl_xor(s1, m);
                s2 += __shfl_xor(s2, m);
            }
            if (lane == 0) {
                red12[0 * 4 + wid] = s0;
                red12[1 * 4 + wid] = s1;
                red12[2 * 4 + wid] = s2;
            }
        }
        __syncthreads();
        if (tid < 3) {
            const float v = red12[tid*4+0] + red12[tid*4+1] + red12[tid*4+2] + red12[tid*4+3];
            atomicAdd(&fcontrib[n * 3 + tid], v);
        }

        vv0 = fmaf(-rx, gx, vv0); vv1 = fmaf(-rx, gy, vv1); vv2 = fmaf(-rx, gz, vv2);
        vv3 = fmaf(-ry, gx, vv3); vv4 = fmaf(-ry, gy, vv4); vv5 = fmaf(-ry, gz, vv5);
        vv6 = fmaf(-rz, gx, vv6); vv7 = fmaf(-rz, gy, vv7); vv8 = fmaf(-rz, gz, vv8);
    }

    {
        float vals[9] = {vv0,vv1,vv2,vv3,vv4,vv5,vv6,vv7,vv8};
        __syncthreads();
#pragma unroll
        for (int i = 0; i < 9; ++i) {
            float v = vals[i];
#pragma unroll
            for (int m = 32; m >= 1; m >>= 1) v += __shfl_xor(v, m);
            if (lane == 0) red12[i * 4 + wid] = v;
        }
        __syncthreads();
        if (tid < 9)
            vir_ws[(size_t)g * 9 + tid] = red12[tid*4+0] + red12[tid*4+1]
                                        + red12[tid*4+2] + red12[tid*4+3];
    }

    __syncthreads();
    {
        float4* dst = reinterpret_cast<float4*>(contrib_ws + (size_t)g * (N_ * 3));
        const float4* src = reinterpret_cast<const float4*>(fcontrib);
        for (int i = tid; i < (N_ * 3) / 4; i += 256) dst[i] = src[i];
    }
}

// ---------------- K3R: sliced column-sum of contrib ----------------
__global__ __launch_bounds__(256) void k3_reduce(
    const float* __restrict__ contrib_ws,
    float* __restrict__ partial_ws)
{
    const int x  = blockIdx.x;          // SL*B_*3 blocks
    const int ch = x % 3;
    const int bb = (x / 3) % B_;
    const int s  = x / (3 * B_);
    const int c4 = ch * 256 + threadIdx.x;
    const int rows = (NG / B_) / SL;
    const int g0 = bb * (NG / B_) + s * rows;

    const float4* src = reinterpret_cast<const float4*>(contrib_ws);
    float4 a0 = {0,0,0,0}, a1 = {0,0,0,0};
    for (int r = 0; r < rows; r += 2) {
        const float4 v0 = src[(size_t)(g0 + r)     * 768 + c4];
        const float4 v1 = src[(size_t)(g0 + r + 1) * 768 + c4];
        a0.x += v0.x; a0.y += v0.y; a0.z += v0.z; a0.w += v0.w;
        a1.x += v1.x; a1.y += v1.y; a1.z += v1.z; a1.w += v1.w;
    }
    const float4 res = {a0.x + a1.x, a0.y + a1.y, a0.z + a1.z, a0.w + a1.w};
    reinterpret_cast<float4*>(partial_ws)[(size_t)(s * B_ + bb) * 768 + c4] = res;
}

// ---------------- K4: finalize Force, Etot, Virial ----------------
__global__ __launch_bounds__(256) void k4_final(
    const float* __restrict__ vir_ws,
    const float* __restrict__ partial_ws,
    float* __restrict__ out)
{
    __shared__ float red[10 * 4];
    const int tid  = threadIdx.x;
    const int lane = tid & 63;
    const int wid  = tid >> 6;
    const int b = blockIdx.x;

    for (int i = tid; i < N_ * 3; i += 256) {
        float f = 0.0f;
#pragma unroll
        for (int s = 0; s < SL; ++s) f += partial_ws[(size_t)(s * B_ + b) * (N_ * 3) + i];
        out[F_OFF + (size_t)b * (N_ * 3) + i] = f;
    }

    float vals[10];
#pragma unroll
    for (int i = 0; i < 10; ++i) vals[i] = 0.0f;
    for (int n = tid; n < N_; n += 256) vals[0] += out[EI_OFF + b * N_ + n];
    {
        const float* vp = vir_ws + ((size_t)b * (NG / B_) + tid) * 9;
#pragma unroll
        for (int j = 0; j < 9; ++j) vals[1 + j] = vp[j];
    }
#pragma unroll
    for (int i = 0; i < 10; ++i) {
        float v = vals[i];
#pragma unroll
        for (int m = 32; m >= 1; m >>= 1) v += __shfl_xor(v, m);
        if (lane == 0) red[i * 4 + wid] = v;
    }
    __syncthreads();
    if (tid < 10) {
        const float v = red[tid*4+0] + red[tid*4+1] + red[tid*4+2] + red[tid*4+3];
        if (tid == 0) out[b] = v;
        else          out[V_OFF + b * 9 + (tid - 1)] = v;
    }
}

extern "C" void kernel_launch(void* const* d_in, const int* in_sizes, int n_in,
                              void* d_out, int out_size, void* d_ws, size_t ws_size,
                              hipStream_t stream) {
    float* out = (float*)d_out;
    float* ws  = (float*)d_ws;
    float* feat_ws    = ws + WS_FEAT;
    float* R_ws       = ws + WS_R;
    float* vir_ws     = ws + WS_VIR;
    float* contrib_ws = ws + WS_CONTRIB;
    float* partial_ws = ws + WS_PARTIAL;

    const int*   list_neigh = (const int*)d_in[0];
    const int*   type_map   = (const int*)d_in[1];
    const float* imagedr    = (const float*)d_in[3];
    const float* c_param    = (const float*)d_in[6];
    const float* scale      = (const float*)d_in[7];
    const float* W0 = (const float*)d_in[8];
    const float* b0 = (const float*)d_in[9];
    const float* W1 = (const float*)d_in[10];
    const float* b1 = (const float*)d_in[11];
    const float* W2 = (const float*)d_in[12];
    const float* b2 = (const float*)d_in[13];
    const float* eshift = (const float*)d_in[14];

    k1_embed<<<B_ * N_, 256, 0, stream>>>(list_neigh, type_map, imagedr, c_param,
                                          scale, feat_ws, R_ws);
    k2_mlp<<<N_, 512, 0, stream>>>(type_map, scale, W0, b0, W1, b1, W2, b2,
                                   eshift, feat_ws, feat_ws /*alias dfeat*/, out);
    k3_bwd<<<NG, 256, 0, stream>>>(list_neigh, type_map, imagedr, c_param,
                                   feat_ws /*dfeat*/, R_ws, contrib_ws, vir_ws);
    k3_reduce<<<SL * B_ * 3, 256, 0, stream>>>(contrib_ws, partial_ws);
    k4_final<<<B_, 256, 0, stream>>>(vir_ws, partial_ws, out);
}

// Round 11
// 207.572 us; speedup vs baseline: 1.1303x; 1.1303x over previous
//
#include <hip/hip_runtime.h>
#include <math.h>

#define RMINF  0.5f
#define LSPAN  5.5f          // RC - RMIN
constexpr int BETA = 12, M1 = 24, M2 = 6;
constexpr int B_ = 4, N_ = 1024, NT_ = 2, MN_ = 128;
constexpr int K_ = NT_ * MN_;        // 256
constexpr int NFEAT = M1 * M2;       // 144
constexpr int HID = 128;
constexpr float PI_F = 3.14159265358979323846f;

// Output layout: Etot(4) | Ei(4096) | Force(4*1024*3) | Virial(36)
constexpr int EI_OFF = B_;                  // 4
constexpr int F_OFF  = B_ + B_ * N_;        // 4100
constexpr int V_OFF  = F_OFF + B_ * N_ * 3; // 16388

constexpr int G_ = 4;                 // source atoms per k3 block
constexpr int NG = B_ * N_ / G_;      // 1024 k3 blocks
constexpr int SL = 8;                 // reduce slices

// Workspace layout (floats); total ~16.9 MB
constexpr size_t WS_FEAT    = 0;                          // 4096*144
constexpr size_t WS_R       = (size_t)B_ * N_ * NFEAT;    // 4096*96
constexpr size_t WS_VIR     = WS_R + (size_t)B_ * N_ * 96;      // 1024*9
constexpr size_t WS_CONTRIB = WS_VIR + (size_t)NG * 9;          // 1024*3072
constexpr size_t WS_PARTIAL = WS_CONTRIB + (size_t)NG * N_ * 3; // 8*4*3072

// Journal:
// - (256,4) launch_bounds -> 64 VGPR -> scratch spill -> 2 GB HBM (r4/r6).
// - r8: spill fixed (VGPR 220, 12 MB, k3 104us).
// - r9: algebraic A/M contraction; k2 4-acc 2n-block: 50us, occ 19.8%.
// - r10: k2 1-acc 512thr: occ 64% but 88us, VALU 15% -> load-latency-bound,
//   reuse-per-load is the lever, not occupancy.
// - r11: k2 = LDS-staged weights (chunked, padded stride 145, fwd + transposed
//   bwd chunks) + 4-acc. Loads become ds_read (~6cy) instead of L2 (~200cy).

// ---------------- K1: embedding forward -> feat, R ----------------
// Algebraic form: M[tk][j][c] = sum_k fc*T_j*sr_c ; R = (c_param . M)/MN.
__global__ __launch_bounds__(256) void k1_embed(
    const int*   __restrict__ list_neigh,
    const int*   __restrict__ type_map,
    const float* __restrict__ imagedr,
    const float* __restrict__ c_param,
    const float* __restrict__ scale,
    float* __restrict__ feat_ws,
    float* __restrict__ R_ws)
{
    __shared__ float c_sh[NT_ * M1 * BETA];   // [tk][f][j] 576
    __shared__ float p_sh[K_][13];            // fc*T_j, padded
    __shared__ float sr_sh[K_][5];
    __shared__ float Mpart[2][96];            // [sub][tk*48 + j*4 + c]
    __shared__ float R_sh[96];

    const int tid = threadIdx.x;
    const int bn = blockIdx.x;
    const int n  = bn % N_;
    const int tn = type_map[n];

    for (int i = tid; i < NT_ * M1 * BETA; i += 256)
        c_sh[i] = c_param[tn * (NT_ * M1 * BETA) + i];

    const int k = tid;
    const int lni = list_neigh[(size_t)bn * K_ + k];
    const float valid = (lni >= 0) ? 1.0f : 0.0f;

    const float4 dr4 = reinterpret_cast<const float4*>(imagedr)[(size_t)bn * K_ + k];
    const float rx = dr4.y, ry = dr4.z, rz = dr4.w;
    const float r  = sqrtf(rx*rx + ry*ry + rz*rz + 1e-12f);
    const float uraw = (r - RMINF) / LSPAN;
    const float u  = fminf(fmaxf(uraw, 0.0f), 1.0f);
    const float fc = 0.5f * (cosf(PI_F * u) + 1.0f) * valid;
    const float x  = 2.0f * (r - RMINF) / LSPAN - 1.0f;

    float T[BETA];
    T[0] = 1.0f; T[1] = x;
#pragma unroll
    for (int j = 2; j < BETA; ++j) T[j] = 2.0f * x * T[j-1] - T[j-2];

    const float inv_r = 1.0f / r;
    sr_sh[k][0] = valid;
    sr_sh[k][1] = valid * rx * inv_r;
    sr_sh[k][2] = valid * ry * inv_r;
    sr_sh[k][3] = valid * rz * inv_r;
#pragma unroll
    for (int j = 0; j < BETA; ++j) p_sh[k][j] = fc * T[j];
    __syncthreads();

    // M partial: 192 threads, each sums 64 neighbors for one (tk,j,c)
    if (tid < 192) {
        const int sub = tid / 96, idx = tid % 96;
        const int tk = idx / 48, rem = idx % 48;
        const int j = rem >> 2, cc = rem & 3;
        const int k0 = tk * 128 + sub * 64;
        float a0 = 0.0f, a1 = 0.0f;
        for (int kk = k0; kk < k0 + 64; kk += 2) {
            a0 = fmaf(p_sh[kk][j],   sr_sh[kk][cc],   a0);
            a1 = fmaf(p_sh[kk+1][j], sr_sh[kk+1][cc], a1);
        }
        Mpart[sub][idx] = a0 + a1;
    }
    __syncthreads();

    // R[f][c] = (1/MN) sum_tk sum_j c[tk][f][j] * M[tk][j][c]
    if (tid < 96) {
        const int f = tid >> 2, cc = tid & 3;
        float acc = 0.0f;
#pragma unroll
        for (int tk = 0; tk < NT_; ++tk) {
#pragma unroll
            for (int j = 0; j < BETA; ++j) {
                const float m = Mpart[0][tk*48 + j*4 + cc] + Mpart[1][tk*48 + j*4 + cc];
                acc = fmaf(c_sh[tk*288 + f*12 + j], m, acc);
            }
        }
        const float v = acc * (1.0f / MN_);
        R_sh[tid] = v;
        R_ws[(size_t)bn * 96 + tid] = v;
    }
    __syncthreads();
    if (tid < NFEAT) {
        const int f = tid / 6, g = tid % 6;
        float acc = 0.0f;
#pragma unroll
        for (int c = 0; c < 4; ++c) acc += R_sh[f * 4 + c] * R_sh[g * 4 + c];
        feat_ws[(size_t)bn * NFEAT + tid] = acc * scale[tid];
    }
}

// ---------------- K2: MLP fwd + bwd, LDS-staged weights ----------------
// One n per block (4 batch rows), 128 threads = columns, 4 accs per thread.
// Weights staged chunk-wise (32 rows x <=144 cols, LDS stride 145):
//   fwd chunks: row-major; bwd chunks: transposed (W1^T, W0^T) so every
//   phase is "stream rows, broadcast activation, FMA into 4 accs".
__global__ __launch_bounds__(128) void k2_mlp(
    const int*   __restrict__ type_map,
    const float* __restrict__ scale,
    const float* __restrict__ W0,
    const float* __restrict__ b0,
    const float* __restrict__ W1,
    const float* __restrict__ b1,
    const float* __restrict__ W2,
    const float* __restrict__ b2,
    const float* __restrict__ eshift,
    const float* __restrict__ feat_ws,
    float* __restrict__ dfeat_ws,     // may alias feat_ws
    float* __restrict__ out)
{
    constexpr int WS = 145;           // padded LDS row stride (odd vs 32 banks)
    __shared__ float feat_sh[4][NFEAT];
    __shared__ float h_sh[4][HID];
    __shared__ float dz1_sh[4][HID];
    __shared__ float dz0_sh[4][HID];
    __shared__ float wbuf[32 * WS];   // 18.6 KB chunk buffer
    __shared__ float red2[4][2];

    const int tid  = threadIdx.x;     // 0..127 = column c
    const int c    = tid;
    const int lane = tid & 63;
    const int wv   = tid >> 6;
    const int n  = blockIdx.x;
    const int tn = type_map[n];

    for (int i = tid; i < 4 * NFEAT; i += 128) {
        const int bb = i / NFEAT, f = i % NFEAT;
        feat_sh[bb][f] = feat_ws[((size_t)bb * N_ + n) * NFEAT + f];
    }

    const float* W0t = W0 + (size_t)tn * NFEAT * HID;
    const float* W1t = W1 + (size_t)tn * HID * HID;

    // ---- layer 0 forward ----
    float acc[4];
    {
        const float bias = b0[tn * HID + c];
        acc[0] = acc[1] = acc[2] = acc[3] = bias;
    }
    for (int ch = 0; ch < NFEAT; ch += 32) {
        const int rows = (NFEAT - ch) < 32 ? (NFEAT - ch) : 32;
        __syncthreads();                       // wbuf free (+ feat_sh published)
        for (int i = tid; i < rows * 128; i += 128) {
            const int f = i >> 7, cc = i & 127;
            wbuf[f * WS + cc] = W0t[(size_t)(ch + f) * HID + cc];
        }
        __syncthreads();
#pragma unroll 4
        for (int f = 0; f < rows; ++f) {
            const float w = wbuf[f * WS + c];
#pragma unroll
            for (int b = 0; b < 4; ++b)
                acc[b] = fmaf(feat_sh[b][ch + f], w, acc[b]);
        }
    }
    float hv[4];
#pragma unroll
    for (int b = 0; b < 4; ++b) { hv[b] = tanhf(acc[b]); h_sh[b][c] = hv[b]; }

    // ---- layer 1 forward ----
    {
        const float bias = b1[tn * HID + c];
        acc[0] = acc[1] = acc[2] = acc[3] = bias;
    }
    for (int ch = 0; ch < HID; ch += 32) {
        __syncthreads();                       // wbuf free (+ h_sh published)
        for (int i = tid; i < 32 * 128; i += 128) {
            const int g = i >> 7, cc = i & 127;
            wbuf[g * WS + cc] = W1t[(size_t)(ch + g) * HID + cc];
        }
        __syncthreads();
#pragma unroll 4
        for (int g = 0; g < 32; ++g) {
            const float w = wbuf[g * WS + c];
#pragma unroll
            for (int b = 0; b < 4; ++b)
                acc[b] = fmaf(h_sh[b][ch + g], w, acc[b]);
        }
    }

    const float w2c = W2[tn * HID + c];
    float ei[4];
#pragma unroll
    for (int b = 0; b < 4; ++b) {
        const float t1 = tanhf(acc[b]);
        dz1_sh[b][c] = w2c * (1.0f - t1 * t1);
        ei[b] = (t1 + hv[b]) * w2c;
    }
#pragma unroll
    for (int b = 0; b < 4; ++b) {
        float v = ei[b];
#pragma unroll
        for (int m = 32; m >= 1; m >>= 1) v += __shfl_xor(v, m);
        if (lane == 0) red2[b][wv] = v;
    }
    __syncthreads();                           // red2 + dz1_sh published
    if (tid < 4)
        out[EI_OFF + (size_t)tid * N_ + n] =
            red2[tid][0] + red2[tid][1] + b2[tn] + eshift[tn];

    // ---- dz0[c] = (w2c + sum_g W1[c][g] dz1[g]) * (1-h^2), via W1^T chunks --
    acc[0] = acc[1] = acc[2] = acc[3] = w2c;
    for (int ch = 0; ch < HID; ch += 32) {
        __syncthreads();                       // wbuf free
        for (int i = tid; i < 32 * 128; i += 128) {
            const int j = i & 31, hh = i >> 5;     // W1T[ch+j][hh] = W1[hh][ch+j]
            wbuf[j * WS + hh] = W1t[(size_t)hh * HID + ch + j];
        }
        __syncthreads();
#pragma unroll 4
        for (int j = 0; j < 32; ++j) {
            const float w = wbuf[j * WS + c];      // = W1[c][ch+j]
#pragma unroll
            for (int b = 0; b < 4; ++b)
                acc[b] = fmaf(dz1_sh[b][ch + j], w, acc[b]);
        }
    }
#pragma unroll
    for (int b = 0; b < 4; ++b) dz0_sh[b][c] = acc[b] * (1.0f - hv[b] * hv[b]);

    // ---- dfeat[f] = scale[f] * sum_h W0[f][h] dz0[h], via W0^T chunks ------
    float d0[4] = {0.f, 0.f, 0.f, 0.f};
    float d1[4] = {0.f, 0.f, 0.f, 0.f};
    for (int ch = 0; ch < HID; ch += 32) {
        __syncthreads();                       // wbuf free (+ dz0_sh published)
        for (int i = tid; i < 32 * NFEAT; i += 128) {   // 4608 = 36*128 exact
            const int j = i & 31, f = i >> 5;           // W0T[ch+j][f] = W0[f][ch+j]
            wbuf[j * WS + f] = W0t[(size_t)f * HID + ch + j];
        }
        __syncthreads();
#pragma unroll 4
        for (int j = 0; j < 32; ++j) {
            const float w = wbuf[j * WS + c];           // = W0[c][ch+j]
            float z[4];
#pragma unroll
            for (int b = 0; b < 4; ++b) z[b] = dz0_sh[b][ch + j];
#pragma unroll
            for (int b = 0; b < 4; ++b) d0[b] = fmaf(w, z[b], d0[b]);
            if (c < NFEAT - HID) {                      // second row f = 128+c
                const float w2 = wbuf[j * WS + HID + c];
#pragma unroll
                for (int b = 0; b < 4; ++b) d1[b] = fmaf(w2, z[b], d1[b]);
            }
        }
    }
    {
        const float sc = scale[c];
#pragma unroll
        for (int b = 0; b < 4; ++b)
            dfeat_ws[((size_t)b * N_ + n) * NFEAT + c] = d0[b] * sc;
        if (c < NFEAT - HID) {
            const float sc2 = scale[HID + c];
#pragma unroll
            for (int b = 0; b < 4; ++b)
                dfeat_ws[((size_t)b * N_ + n) * NFEAT + HID + c] = d1[b] * sc2;
        }
    }
}

// ---------------- K3: embedding backward via A = c . dR ------------------
__global__ __launch_bounds__(256) void k3_bwd(
    const int*   __restrict__ list_neigh,
    const int*   __restrict__ type_map,
    const float* __restrict__ imagedr,
    const float* __restrict__ c_param,
    const float* __restrict__ dfeat_ws,
    const float* __restrict__ R_ws,
    float* __restrict__ contrib_ws,
    float* __restrict__ vir_ws)
{
    __shared__ float fcontrib[N_ * 3];      // 12 KB force image
    __shared__ float c_sh[NT_ * M1 * BETA];
    __shared__ float dfeat_sh[NFEAT];
    __shared__ float R_sh[96];
    __shared__ float dR_sh[96];
    __shared__ float A_sh[96];              // [tk][j][c]
    __shared__ float red12[12 * 4];

    const int tid  = threadIdx.x;
    const int lane = tid & 63;
    const int wid  = tid >> 6;
    const int g  = blockIdx.x;
    const int tk = tid >> 7;

    for (int i = tid; i < N_ * 3; i += 256) fcontrib[i] = 0.0f;

    float vv0=0.f,vv1=0.f,vv2=0.f,vv3=0.f,vv4=0.f,vv5=0.f,vv6=0.f,vv7=0.f,vv8=0.f;

    for (int aa = 0; aa < G_; ++aa) {
        const int bn = g * G_ + aa;
        const int n  = bn & (N_ - 1);
        const int tn = type_map[n];

        __syncthreads();
        for (int i = tid; i < NT_ * M1 * BETA; i += 256)
            c_sh[i] = c_param[tn * (NT_ * M1 * BETA) + i];
        if (tid < NFEAT) dfeat_sh[tid] = dfeat_ws[(size_t)bn * NFEAT + tid];
        if (tid < 96)    R_sh[tid]     = R_ws[(size_t)bn * 96 + tid];
        __syncthreads();

        if (tid < 96) {
            const int p = tid >> 2, c = tid & 3;
            float acc = 0.0f;
#pragma unroll
            for (int gg = 0; gg < M2; ++gg) acc += dfeat_sh[p * 6 + gg] * R_sh[gg * 4 + c];
            if (p < M2) {
                for (int f = 0; f < M1; ++f) acc += dfeat_sh[f * 6 + p] * R_sh[f * 4 + c];
            }
            dR_sh[p * 4 + c] = acc * (1.0f / MN_);
        }
        __syncthreads();

        // A[tk][j][c] = sum_f c[tk][f][j] * dR[f][c]
        if (tid < 96) {
            const int atk = tid / 48, rem = tid % 48;
            const int j = rem >> 2, cc = rem & 3;
            float acc = 0.0f;
#pragma unroll
            for (int f = 0; f < M1; ++f)
                acc = fmaf(c_sh[atk*288 + f*12 + j], dR_sh[f*4 + cc], acc);
            A_sh[tid] = acc;
        }
        __syncthreads();

        const int lni = list_neigh[(size_t)bn * K_ + tid];
        const float valid = (lni >= 0) ? 1.0f : 0.0f;
        const float4 dr4 = reinterpret_cast<const float4*>(imagedr)[(size_t)bn * K_ + tid];
        const float rx = dr4.y, ry = dr4.z, rz = dr4.w;
        const float r  = sqrtf(rx*rx + ry*ry + rz*rz + 1e-12f);
        const float uraw = (r - RMINF) / LSPAN;
        const float u  = fminf(fmaxf(uraw, 0.0f), 1.0f);
        const float fc = 0.5f * (cosf(PI_F * u) + 1.0f) * valid;
        const float x  = 2.0f * (r - RMINF) / LSPAN - 1.0f;

        float T[BETA];
        T[0] = 1.0f; T[1] = x;
#pragma unroll
        for (int j = 2; j < BETA; ++j) T[j] = 2.0f * x * T[j-1] - T[j-2];

        const float inv_r = 1.0f / r;
        const float sr0 = valid;
        const float sr1 = valid * rx * inv_r;
        const float sr2 = valid * ry * inv_r;
        const float sr3 = valid * rz * inv_r;

        // single 12-iter contraction: cj_j = A[j].sr ; dfc = T.cj ;
        // tA_c = T.A[:,c] ; dx = cj.T'
        const float* Arow = &A_sh[tk * 48];
        float dfc = 0.0f, dx = 0.0f;
        float tA0 = 0.0f, tA1 = 0.0f, tA2 = 0.0f, tA3 = 0.0f;
        float tpm1 = 1.0f, tpm2 = 0.0f;
#pragma unroll
        for (int j = 0; j < BETA; ++j) {
            const float a0 = Arow[j*4+0], a1 = Arow[j*4+1];
            const float a2 = Arow[j*4+2], a3 = Arow[j*4+3];
            const float cjj = a0*sr0 + a1*sr1 + a2*sr2 + a3*sr3;
            dfc = fmaf(T[j], cjj, dfc);
            tA0 = fmaf(T[j], a0, tA0);
            tA1 = fmaf(T[j], a1, tA1);
            tA2 = fmaf(T[j], a2, tA2);
            tA3 = fmaf(T[j], a3, tA3);
            if (j == 1) {
                dx = cjj;                  // T'_1 = 1
            } else if (j >= 2) {
                const float tp = 2.0f * T[j-1] + 2.0f * x * tpm1 - tpm2;
                dx = fmaf(cjj, tp, dx);
                tpm2 = tpm1; tpm1 = tp;
            }
        }
        const float dsr1 = fc * tA1, dsr2 = fc * tA2, dsr3 = fc * tA3;

        float dfcdr = 0.0f;
        if (uraw > 0.0f && uraw < 1.0f)
            dfcdr = -0.5f * PI_F * sinf(PI_F * u) * valid / LSPAN;
        const float drt = (fc * dx) * (2.0f / LSPAN) + dfc * dfcdr;
        const float Sdot = dsr1 * rx + dsr2 * ry + dsr3 * rz;
        const float common = drt * inv_r - valid * Sdot * inv_r * inv_r * inv_r;
        const float gx = common * rx + valid * dsr1 * inv_r;
        const float gy = common * ry + valid * dsr2 * inv_r;
        const float gz = common * rz + valid * dsr3 * inv_r;

        if (lni >= 0) {
            atomicAdd(&fcontrib[lni * 3 + 0], -gx);
            atomicAdd(&fcontrib[lni * 3 + 1], -gy);
            atomicAdd(&fcontrib[lni * 3 + 2], -gz);
        }

        {
            float s0 = gx, s1 = gy, s2 = gz;
#pragma unroll
            for (int m = 32; m >= 1; m >>= 1) {
                s0 += __shfl_xor(s0, m);
                s1 += __shfl_xor(s1, m);
                s2 += __shfl_xor(s2, m);
            }
            if (lane == 0) {
                red12[0 * 4 + wid] = s0;
                red12[1 * 4 + wid] = s1;
                red12[2 * 4 + wid] = s2;
            }
        }
        __syncthreads();
        if (tid < 3) {
            const float v = red12[tid*4+0] + red12[tid*4+1] + red12[tid*4+2] + red12[tid*4+3];
            atomicAdd(&fcontrib[n * 3 + tid], v);
        }

        vv0 = fmaf(-rx, gx, vv0); vv1 = fmaf(-rx, gy, vv1); vv2 = fmaf(-rx, gz, vv2);
        vv3 = fmaf(-ry, gx, vv3); vv4 = fmaf(-ry, gy, vv4); vv5 = fmaf(-ry, gz, vv5);
        vv6 = fmaf(-rz, gx, vv6); vv7 = fmaf(-rz, gy, vv7); vv8 = fmaf(-rz, gz, vv8);
    }

    {
        float vals[9] = {vv0,vv1,vv2,vv3,vv4,vv5,vv6,vv7,vv8};
        __syncthreads();
#pragma unroll
        for (int i = 0; i < 9; ++i) {
            float v = vals[i];
#pragma unroll
            for (int m = 32; m >= 1; m >>= 1) v += __shfl_xor(v, m);
            if (lane == 0) red12[i * 4 + wid] = v;
        }
        __syncthreads();
        if (tid < 9)
            vir_ws[(size_t)g * 9 + tid] = red12[tid*4+0] + red12[tid*4+1]
                                        + red12[tid*4+2] + red12[tid*4+3];
    }

    __syncthreads();
    {
        float4* dst = reinterpret_cast<float4*>(contrib_ws + (size_t)g * (N_ * 3));
        const float4* src = reinterpret_cast<const float4*>(fcontrib);
        for (int i = tid; i < (N_ * 3) / 4; i += 256) dst[i] = src[i];
    }
}

// ---------------- K3R: sliced column-sum of contrib ----------------
__global__ __launch_bounds__(256) void k3_reduce(
    const float* __restrict__ contrib_ws,
    float* __restrict__ partial_ws)
{
    const int x  = blockIdx.x;          // SL*B_*3 blocks
    const int ch = x % 3;
    const int bb = (x / 3) % B_;
    const int s  = x / (3 * B_);
    const int c4 = ch * 256 + threadIdx.x;
    const int rows = (NG / B_) / SL;
    const int g0 = bb * (NG / B_) + s * rows;

    const float4* src = reinterpret_cast<const float4*>(contrib_ws);
    float4 a0 = {0,0,0,0}, a1 = {0,0,0,0};
    for (int r = 0; r < rows; r += 2) {
        const float4 v0 = src[(size_t)(g0 + r)     * 768 + c4];
        const float4 v1 = src[(size_t)(g0 + r + 1) * 768 + c4];
        a0.x += v0.x; a0.y += v0.y; a0.z += v0.z; a0.w += v0.w;
        a1.x += v1.x; a1.y += v1.y; a1.z += v1.z; a1.w += v1.w;
    }
    const float4 res = {a0.x + a1.x, a0.y + a1.y, a0.z + a1.z, a0.w + a1.w};
    reinterpret_cast<float4*>(partial_ws)[(size_t)(s * B_ + bb) * 768 + c4] = res;
}

// ---------------- K4: finalize Force, Etot, Virial ----------------
__global__ __launch_bounds__(256) void k4_final(
    const float* __restrict__ vir_ws,
    const float* __restrict__ partial_ws,
    float* __restrict__ out)
{
    __shared__ float red[10 * 4];
    const int tid  = threadIdx.x;
    const int lane = tid & 63;
    const int wid  = tid >> 6;
    const int b = blockIdx.x;

    for (int i = tid; i < N_ * 3; i += 256) {
        float f = 0.0f;
#pragma unroll
        for (int s = 0; s < SL; ++s) f += partial_ws[(size_t)(s * B_ + b) * (N_ * 3) + i];
        out[F_OFF + (size_t)b * (N_ * 3) + i] = f;
    }

    float vals[10];
#pragma unroll
    for (int i = 0; i < 10; ++i) vals[i] = 0.0f;
    for (int n = tid; n < N_; n += 256) vals[0] += out[EI_OFF + b * N_ + n];
    {
        const float* vp = vir_ws + ((size_t)b * (NG / B_) + tid) * 9;
#pragma unroll
        for (int j = 0; j < 9; ++j) vals[1 + j] = vp[j];
    }
#pragma unroll
    for (int i = 0; i < 10; ++i) {
        float v = vals[i];
#pragma unroll
        for (int m = 32; m >= 1; m >>= 1) v += __shfl_xor(v, m);
        if (lane == 0) red[i * 4 + wid] = v;
    }
    __syncthreads();
    if (tid < 10) {
        const float v = red[tid*4+0] + red[tid*4+1] + red[tid*4+2] + red[tid*4+3];
        if (tid == 0) out[b] = v;
        else          out[V_OFF + b * 9 + (tid - 1)] = v;
    }
}

extern "C" void kernel_launch(void* const* d_in, const int* in_sizes, int n_in,
                              void* d_out, int out_size, void* d_ws, size_t ws_size,
                              hipStream_t stream) {
    float* out = (float*)d_out;
    float* ws  = (float*)d_ws;
    float* feat_ws    = ws + WS_FEAT;
    float* R_ws       = ws + WS_R;
    float* vir_ws     = ws + WS_VIR;
    float* contrib_ws = ws + WS_CONTRIB;
    float* partial_ws = ws + WS_PARTIAL;

    const int*   list_neigh = (const int*)d_in[0];
    const int*   type_map   = (const int*)d_in[1];
    const float* imagedr    = (const float*)d_in[3];
    const float* c_param    = (const float*)d_in[6];
    const float* scale      = (const float*)d_in[7];
    const float* W0 = (const float*)d_in[8];
    const float* b0 = (const float*)d_in[9];
    const float* W1 = (const float*)d_in[10];
    const float* b1 = (const float*)d_in[11];
    const float* W2 = (const float*)d_in[12];
    const float* b2 = (const float*)d_in[13];
    const float* eshift = (const float*)d_in[14];

    k1_embed<<<B_ * N_, 256, 0, stream>>>(list_neigh, type_map, imagedr, c_param,
                                          scale, feat_ws, R_ws);
    k2_mlp<<<N_, 128, 0, stream>>>(type_map, scale, W0, b0, W1, b1, W2, b2,
                                   eshift, feat_ws, feat_ws /*alias dfeat*/, out);
    k3_bwd<<<NG, 256, 0, stream>>>(list_neigh, type_map, imagedr, c_param,
                                   feat_ws /*dfeat*/, R_ws, contrib_ws, vir_ws);
    k3_reduce<<<SL * B_ * 3, 256, 0, stream>>>(contrib_ws, partial_ws);
    k4_final<<<B_, 256, 0, stream>>>(vir_ws, partial_ws, out);
}

// Round 12
// 202.287 us; speedup vs baseline: 1.1599x; 1.0261x over previous
//
#include <hip/hip_runtime.h>
#include <math.h>

#define RMINF  0.5f
#define LSPAN  5.5f          // RC - RMIN
constexpr int BETA = 12, M1 = 24, M2 = 6;
constexpr int B_ = 4, N_ = 1024, NT_ = 2, MN_ = 128;
constexpr int K_ = NT_ * MN_;        // 256
constexpr int NFEAT = M1 * M2;       // 144
constexpr int HID = 128;
constexpr float PI_F = 3.14159265358979323846f;

// Output layout: Etot(4) | Ei(4096) | Force(4*1024*3) | Virial(36)
constexpr int EI_OFF = B_;                  // 4
constexpr int F_OFF  = B_ + B_ * N_;        // 4100
constexpr int V_OFF  = F_OFF + B_ * N_ * 3; // 16388

constexpr int G3 = 8;                  // source atoms per k3 block
constexpr int NG3 = B_ * N_ / G3;      // 512 k3 blocks
constexpr int SL = 8;                  // reduce slices
constexpr int NTILE = 258;             // k2 tiles (1032/4)

// Workspace layout (floats)
constexpr size_t WS_FEAT    = 0;                                 // 4096*144
constexpr size_t WS_R       = (size_t)B_ * N_ * NFEAT;           // 4096*96
constexpr size_t WS_A       = WS_R + (size_t)B_ * N_ * 96;       // 4096*96
constexpr size_t WS_VIR     = WS_A + (size_t)B_ * N_ * 96;       // 512*9
constexpr size_t WS_CONTRIB = WS_VIR + (size_t)NG3 * 9;          // 512*3072
constexpr size_t WS_PARTIAL = WS_CONTRIB + (size_t)NG3 * N_ * 3; // 8*4*3072
constexpr size_t WS_SITES   = WS_PARTIAL + (size_t)SL * B_ * N_ * 3; // 1032 ints

// Journal:
// - (256,4) launch_bounds -> 64 VGPR -> scratch spill -> 2 GB HBM (r4/r6).
// - r8: spill fixed. r9: algebraic A/M contraction (k3 104->40ish, k2 50).
// - r10: k2 1-acc/512thr: occ 64% but 88us -> reuse-per-load is the lever.
// - r11: k2 LDS-staged weights: 61us; model shows LDS-ISSUE bound
//   (5 ds_read per 4 FMA). r12: same-type 16-atom tiles (k0 sort) ->
//   3 ds_read per 8 FMA; k3's per-atom prep phases -> k3a (A_ws); k3 G=8.

// ---------------- K0: type-sorted, 4-padded site list ----------------
__global__ void k0_sort(const int* __restrict__ type_map, int* __restrict__ sites)
{
    __shared__ int counts[2];
    __shared__ int base[2];
    __shared__ int cursor[2];
    const int tid = threadIdx.x;
    if (tid < 2) { counts[tid] = 0; cursor[tid] = 0; }
    for (int i = tid; i < NTILE * 4; i += 1024) sites[i] = -1;
    __syncthreads();
    int myt = -1;
    if (tid < N_) { myt = type_map[tid]; atomicAdd(&counts[myt], 1); }
    __syncthreads();
    if (tid == 0) { base[0] = 0; base[1] = ((counts[0] + 3) >> 2) << 2; }
    __syncthreads();
    if (tid < N_) {
        const int p = atomicAdd(&cursor[myt], 1);
        sites[base[myt] + p] = tid;
    }
}

// ---------------- K1: embedding forward -> feat, R ----------------
__global__ __launch_bounds__(256) void k1_embed(
    const int*   __restrict__ list_neigh,
    const int*   __restrict__ type_map,
    const float* __restrict__ imagedr,
    const float* __restrict__ c_param,
    const float* __restrict__ scale,
    float* __restrict__ feat_ws,
    float* __restrict__ R_ws)
{
    __shared__ float c_sh[NT_ * M1 * BETA];   // [tk][f][j] 576
    __shared__ float p_sh[K_][13];            // fc*T_j, padded
    __shared__ float sr_sh[K_][5];
    __shared__ float Mpart[2][96];            // [sub][tk*48 + j*4 + c]
    __shared__ float R_sh[96];

    const int tid = threadIdx.x;
    const int bn = blockIdx.x;
    const int n  = bn % N_;
    const int tn = type_map[n];

    for (int i = tid; i < NT_ * M1 * BETA; i += 256)
        c_sh[i] = c_param[tn * (NT_ * M1 * BETA) + i];

    const int k = tid;
    const int lni = list_neigh[(size_t)bn * K_ + k];
    const float valid = (lni >= 0) ? 1.0f : 0.0f;

    const float4 dr4 = reinterpret_cast<const float4*>(imagedr)[(size_t)bn * K_ + k];
    const float rx = dr4.y, ry = dr4.z, rz = dr4.w;
    const float r  = sqrtf(rx*rx + ry*ry + rz*rz + 1e-12f);
    const float uraw = (r - RMINF) / LSPAN;
    const float u  = fminf(fmaxf(uraw, 0.0f), 1.0f);
    const float fc = 0.5f * (cosf(PI_F * u) + 1.0f) * valid;
    const float x  = 2.0f * (r - RMINF) / LSPAN - 1.0f;

    float T[BETA];
    T[0] = 1.0f; T[1] = x;
#pragma unroll
    for (int j = 2; j < BETA; ++j) T[j] = 2.0f * x * T[j-1] - T[j-2];

    const float inv_r = 1.0f / r;
    sr_sh[k][0] = valid;
    sr_sh[k][1] = valid * rx * inv_r;
    sr_sh[k][2] = valid * ry * inv_r;
    sr_sh[k][3] = valid * rz * inv_r;
#pragma unroll
    for (int j = 0; j < BETA; ++j) p_sh[k][j] = fc * T[j];
    __syncthreads();

    if (tid < 192) {
        const int sub = tid / 96, idx = tid % 96;
        const int tk = idx / 48, rem = idx % 48;
        const int j = rem >> 2, cc = rem & 3;
        const int k0 = tk * 128 + sub * 64;
        float a0 = 0.0f, a1 = 0.0f;
        for (int kk = k0; kk < k0 + 64; kk += 2) {
            a0 = fmaf(p_sh[kk][j],   sr_sh[kk][cc],   a0);
            a1 = fmaf(p_sh[kk+1][j], sr_sh[kk+1][cc], a1);
        }
        Mpart[sub][idx] = a0 + a1;
    }
    __syncthreads();

    if (tid < 96) {
        const int f = tid >> 2, cc = tid & 3;
        float acc = 0.0f;
#pragma unroll
        for (int tk = 0; tk < NT_; ++tk) {
#pragma unroll
            for (int j = 0; j < BETA; ++j) {
                const float m = Mpart[0][tk*48 + j*4 + cc] + Mpart[1][tk*48 + j*4 + cc];
                acc = fmaf(c_sh[tk*288 + f*12 + j], m, acc);
            }
        }
        const float v = acc * (1.0f / MN_);
        R_sh[tid] = v;
        R_ws[(size_t)bn * 96 + tid] = v;
    }
    __syncthreads();
    if (tid < NFEAT) {
        const int f = tid / 6, g = tid % 6;
        float acc = 0.0f;
#pragma unroll
        for (int c = 0; c < 4; ++c) acc += R_sh[f * 4 + c] * R_sh[g * 4 + c];
        feat_ws[(size_t)bn * NFEAT + tid] = acc * scale[tid];
    }
}

// ---------------- K2: MLP fwd+bwd, 16 same-type atoms per block ----------
// Tile = 4 sites x 4 batches. 256 thr = (col c 0..127) x (half 0/1).
// Each thread: 8 atom-rows (half*8..half*8+7), row r = si*4+bb.
// Activations in LDS as [row][16 atoms] pad 20 -> b128 broadcast reads.
// Weights chunk-staged in wbuf stride 145 (conflict-free both layouts).
__global__ __launch_bounds__(256) void k2_mlp(
    const int*   __restrict__ type_map,
    const float* __restrict__ scale,
    const float* __restrict__ W0,
    const float* __restrict__ b0,
    const float* __restrict__ W1,
    const float* __restrict__ b1,
    const float* __restrict__ W2,
    const float* __restrict__ b2,
    const float* __restrict__ eshift,
    const float* __restrict__ feat_ws,
    float* __restrict__ dfeat_ws,     // may alias feat_ws
    float* __restrict__ out,
    const int* __restrict__ sites)
{
    constexpr int WSR = 145;
    __shared__ float feat2[NFEAT * 20];   // [f][16 pad 20]
    __shared__ float h2[HID * 20];
    __shared__ float dz1_2[HID * 20];
    __shared__ float dz0_2[HID * 20];
    __shared__ float wbuf[32 * WSR];
    __shared__ float red[4][8];
    __shared__ int   s_sh[4];

    const int tid  = threadIdx.x;
    const int c    = tid & 127;
    const int half = tid >> 7;
    const int lane = tid & 63;
    const int wid  = tid >> 6;

    if (tid < 4) s_sh[tid] = sites[blockIdx.x * 4 + tid];
    __syncthreads();
    int sarr[4];
#pragma unroll
    for (int i = 0; i < 4; ++i) sarr[i] = s_sh[i];
    const int sv = sarr[0] >= 0 ? sarr[0] : (sarr[1] >= 0 ? sarr[1]
                 : (sarr[2] >= 0 ? sarr[2] : sarr[3]));
    if (sv < 0) return;
    const int tn = type_map[sv];

    // stage feat2[f][r]
    for (int r = 0; r < 16; ++r) {
        const int si = r >> 2, bb = r & 3;
        const int s = sarr[si];
        if (tid < NFEAT)
            feat2[tid * 20 + r] = (s >= 0)
                ? feat_ws[((size_t)bb * N_ + s) * NFEAT + tid] : 0.0f;
    }

    const float* W0t = W0 + (size_t)tn * NFEAT * HID;
    const float* W1t = W1 + (size_t)tn * HID * HID;

    // ---- layer 0 ----
    float acc[8];
    {
        const float bias = b0[tn * HID + c];
#pragma unroll
        for (int a = 0; a < 8; ++a) acc[a] = bias;
    }
    for (int ch = 0; ch < NFEAT; ch += 32) {
        const int rows = (NFEAT - ch) < 32 ? (NFEAT - ch) : 32;
        __syncthreads();
        for (int i = tid; i < rows * 128; i += 256) {
            const int f = i >> 7, cc = i & 127;
            wbuf[f * WSR + cc] = W0t[(size_t)(ch + f) * HID + cc];
        }
        __syncthreads();
#pragma unroll 4
        for (int f0 = 0; f0 < rows; ++f0) {
            const float w = wbuf[f0 * WSR + c];
            const float4 fa = *reinterpret_cast<const float4*>(&feat2[(ch+f0)*20 + half*8]);
            const float4 fb = *reinterpret_cast<const float4*>(&feat2[(ch+f0)*20 + half*8 + 4]);
            acc[0] = fmaf(fa.x, w, acc[0]); acc[1] = fmaf(fa.y, w, acc[1]);
            acc[2] = fmaf(fa.z, w, acc[2]); acc[3] = fmaf(fa.w, w, acc[3]);
            acc[4] = fmaf(fb.x, w, acc[4]); acc[5] = fmaf(fb.y, w, acc[5]);
            acc[6] = fmaf(fb.z, w, acc[6]); acc[7] = fmaf(fb.w, w, acc[7]);
        }
    }
    float hv[8];
#pragma unroll
    for (int a = 0; a < 8; ++a) {
        hv[a] = tanhf(acc[a]);
        h2[c * 20 + half * 8 + a] = hv[a];
    }

    // ---- layer 1 ----
    {
        const float bias = b1[tn * HID + c];
#pragma unroll
        for (int a = 0; a < 8; ++a) acc[a] = bias;
    }
    for (int ch = 0; ch < HID; ch += 32) {
        __syncthreads();                   // h2 published / wbuf free
        for (int i = tid; i < 32 * 128; i += 256) {
            const int g = i >> 7, cc = i & 127;
            wbuf[g * WSR + cc] = W1t[(size_t)(ch + g) * HID + cc];
        }
        __syncthreads();
#pragma unroll 4
        for (int g0 = 0; g0 < 32; ++g0) {
            const float w = wbuf[g0 * WSR + c];
            const float4 ha = *reinterpret_cast<const float4*>(&h2[(ch+g0)*20 + half*8]);
            const float4 hb = *reinterpret_cast<const float4*>(&h2[(ch+g0)*20 + half*8 + 4]);
            acc[0] = fmaf(ha.x, w, acc[0]); acc[1] = fmaf(ha.y, w, acc[1]);
            acc[2] = fmaf(ha.z, w, acc[2]); acc[3] = fmaf(ha.w, w, acc[3]);
            acc[4] = fmaf(hb.x, w, acc[4]); acc[5] = fmaf(hb.y, w, acc[5]);
            acc[6] = fmaf(hb.z, w, acc[6]); acc[7] = fmaf(hb.w, w, acc[7]);
        }
    }

    const float w2c = W2[tn * HID + c];
    float ei[8];
#pragma unroll
    for (int a = 0; a < 8; ++a) {
        const float t1 = tanhf(acc[a]);
        dz1_2[c * 20 + half * 8 + a] = w2c * (1.0f - t1 * t1);
        ei[a] = (t1 + hv[a]) * w2c;
    }
#pragma unroll
    for (int a = 0; a < 8; ++a) {
        float v = ei[a];
#pragma unroll
        for (int m = 32; m >= 1; m >>= 1) v += __shfl_xor(v, m);
        if (lane == 0) red[wid][a] = v;
    }
    __syncthreads();                       // red + dz1_2 published
    if (tid < 16) {
        const int hh = tid >> 3, a = tid & 7;
        const int si = tid >> 2, bb = tid & 3;
        const int s = sarr[si];
        if (s >= 0)
            out[EI_OFF + (size_t)bb * N_ + s] =
                red[hh*2][a] + red[hh*2+1][a] + b2[tn] + eshift[tn];
    }

    // ---- dz0 = (w2 + W1^T-chunks . dz1) * (1-h^2) ----
#pragma unroll
    for (int a = 0; a < 8; ++a) acc[a] = w2c;
    for (int ch = 0; ch < HID; ch += 32) {
        __syncthreads();
        for (int i = tid; i < 32 * 128; i += 256) {
            const int j = i & 31, hh = i >> 5;
            wbuf[j * WSR + hh] = W1t[(size_t)hh * HID + ch + j];
        }
        __syncthreads();
#pragma unroll 4
        for (int j = 0; j < 32; ++j) {
            const float w = wbuf[j * WSR + c];     // = W1[c][ch+j]
            const float4 za = *reinterpret_cast<const float4*>(&dz1_2[(ch+j)*20 + half*8]);
            const float4 zb = *reinterpret_cast<const float4*>(&dz1_2[(ch+j)*20 + half*8 + 4]);
            acc[0] = fmaf(za.x, w, acc[0]); acc[1] = fmaf(za.y, w, acc[1]);
            acc[2] = fmaf(za.z, w, acc[2]); acc[3] = fmaf(za.w, w, acc[3]);
            acc[4] = fmaf(zb.x, w, acc[4]); acc[5] = fmaf(zb.y, w, acc[5]);
            acc[6] = fmaf(zb.z, w, acc[6]); acc[7] = fmaf(zb.w, w, acc[7]);
        }
    }
#pragma unroll
    for (int a = 0; a < 8; ++a)
        dz0_2[c * 20 + half * 8 + a] = acc[a] * (1.0f - hv[a] * hv[a]);

    // ---- dfeat = scale * (W0^T-chunks . dz0) ----
    float d0[8] = {0,0,0,0,0,0,0,0};
    float d1[8] = {0,0,0,0,0,0,0,0};
    const int c2 = (c < NFEAT - HID) ? (HID + c) : HID;   // clamped in-row idx
    for (int ch = 0; ch < HID; ch += 32) {
        __syncthreads();                   // dz0_2 published / wbuf free
        for (int i = tid; i < 32 * NFEAT; i += 256) {
            const int j = i & 31, f = i >> 5;
            wbuf[j * WSR + f] = W0t[(size_t)f * HID + ch + j];
        }
        __syncthreads();
#pragma unroll 4
        for (int j = 0; j < 32; ++j) {
            const float w  = wbuf[j * WSR + c];    // = W0[c][ch+j]
            const float w2 = wbuf[j * WSR + c2];   // = W0[128+c][ch+j] (c<16)
            const float4 za = *reinterpret_cast<const float4*>(&dz0_2[(ch+j)*20 + half*8]);
            const float4 zb = *reinterpret_cast<const float4*>(&dz0_2[(ch+j)*20 + half*8 + 4]);
            d0[0] = fmaf(za.x, w, d0[0]); d0[1] = fmaf(za.y, w, d0[1]);
            d0[2] = fmaf(za.z, w, d0[2]); d0[3] = fmaf(za.w, w, d0[3]);
            d0[4] = fmaf(zb.x, w, d0[4]); d0[5] = fmaf(zb.y, w, d0[5]);
            d0[6] = fmaf(zb.z, w, d0[6]); d0[7] = fmaf(zb.w, w, d0[7]);
            d1[0] = fmaf(za.x, w2, d1[0]); d1[1] = fmaf(za.y, w2, d1[1]);
            d1[2] = fmaf(za.z, w2, d1[2]); d1[3] = fmaf(za.w, w2, d1[3]);
            d1[4] = fmaf(zb.x, w2, d1[4]); d1[5] = fmaf(zb.y, w2, d1[5]);
            d1[6] = fmaf(zb.z, w2, d1[6]); d1[7] = fmaf(zb.w, w2, d1[7]);
        }
    }
    {
        const float sc  = scale[c];
        const float sc2 = (c < NFEAT - HID) ? scale[HID + c] : 0.0f;
#pragma unroll
        for (int a = 0; a < 8; ++a) {
            const int r = half * 8 + a;
            const int si = r >> 2, bb = r & 3;
            const int s = sarr[si];
            if (s >= 0) {
                dfeat_ws[((size_t)bb * N_ + s) * NFEAT + c] = d0[a] * sc;
                if (c < NFEAT - HID)
                    dfeat_ws[((size_t)bb * N_ + s) * NFEAT + HID + c] = d1[a] * sc2;
            }
        }
    }
}

// ---------------- K3a: per-atom dR + A precompute ----------------
__global__ __launch_bounds__(256) void k3a_prep(
    const int*   __restrict__ type_map,
    const float* __restrict__ c_param,
    const float* __restrict__ dfeat_ws,
    const float* __restrict__ R_ws,
    float* __restrict__ A_ws)
{
    __shared__ float call[NT_ * NT_ * M1 * BETA];   // 1152: whole c_param
    __shared__ float df[2][NFEAT];
    __shared__ float R2[2][96];
    __shared__ float dR2[2][96];

    const int tid = threadIdx.x;
    const int bn0 = blockIdx.x * 2;

    for (int i = tid; i < NT_ * NT_ * M1 * BETA; i += 256) call[i] = c_param[i];
    for (int i = tid; i < 2 * NFEAT; i += 256)
        df[i / NFEAT][i % NFEAT] = dfeat_ws[(size_t)(bn0 + i / NFEAT) * NFEAT + i % NFEAT];
    for (int i = tid; i < 2 * 96; i += 256)
        R2[i / 96][i % 96] = R_ws[(size_t)(bn0 + i / 96) * 96 + i % 96];
    __syncthreads();

    if (tid < 192) {
        const int at = tid / 96, idx = tid % 96;
        const int p = idx >> 2, cc = idx & 3;
        float a = 0.0f;
#pragma unroll
        for (int gg = 0; gg < M2; ++gg) a += df[at][p * 6 + gg] * R2[at][gg * 4 + cc];
        if (p < M2) {
            for (int f = 0; f < M1; ++f) a += df[at][f * 6 + p] * R2[at][f * 4 + cc];
        }
        dR2[at][idx] = a * (1.0f / MN_);
    }
    __syncthreads();
    if (tid < 192) {
        const int at = tid / 96, idx = tid % 96;
        const int tkk = idx / 48, rem = idx % 48;
        const int j = rem >> 2, cc = rem & 3;
        const int tnat = type_map[(bn0 + at) & (N_ - 1)];
        float a = 0.0f;
#pragma unroll
        for (int f = 0; f < M1; ++f)
            a = fmaf(call[tnat * 576 + tkk * 288 + f * 12 + j], dR2[at][f * 4 + cc], a);
        A_ws[(size_t)(bn0 + at) * 96 + idx] = a;
    }
}

// ---------------- K3: neighbor backward, G3 atoms/block, LDS force image --
__global__ __launch_bounds__(256) void k3_bwd(
    const int*   __restrict__ list_neigh,
    const float* __restrict__ imagedr,
    const float* __restrict__ A_ws,
    float* __restrict__ contrib_ws,
    float* __restrict__ vir_ws)
{
    __shared__ float fcontrib[N_ * 3];      // 12 KB force image
    __shared__ float A_sh[96];
    __shared__ float red12[12 * 4];

    const int tid  = threadIdx.x;
    const int lane = tid & 63;
    const int wid  = tid >> 6;
    const int g  = blockIdx.x;              // 0..NG3-1
    const int tk = tid >> 7;

    for (int i = tid; i < N_ * 3; i += 256) fcontrib[i] = 0.0f;

    float vv0=0.f,vv1=0.f,vv2=0.f,vv3=0.f,vv4=0.f,vv5=0.f,vv6=0.f,vv7=0.f,vv8=0.f;

    for (int aa = 0; aa < G3; ++aa) {
        const int bn = g * G3 + aa;
        const int n  = bn & (N_ - 1);

        __syncthreads();                    // A_sh free / fcontrib zero done
        if (tid < 96) A_sh[tid] = A_ws[(size_t)bn * 96 + tid];
        __syncthreads();

        const int lni = list_neigh[(size_t)bn * K_ + tid];
        const float valid = (lni >= 0) ? 1.0f : 0.0f;
        const float4 dr4 = reinterpret_cast<const float4*>(imagedr)[(size_t)bn * K_ + tid];
        const float rx = dr4.y, ry = dr4.z, rz = dr4.w;
        const float r  = sqrtf(rx*rx + ry*ry + rz*rz + 1e-12f);
        const float uraw = (r - RMINF) / LSPAN;
        const float u  = fminf(fmaxf(uraw, 0.0f), 1.0f);
        const float fc = 0.5f * (cosf(PI_F * u) + 1.0f) * valid;
        const float x  = 2.0f * (r - RMINF) / LSPAN - 1.0f;

        float T[BETA];
        T[0] = 1.0f; T[1] = x;
#pragma unroll
        for (int j = 2; j < BETA; ++j) T[j] = 2.0f * x * T[j-1] - T[j-2];

        const float inv_r = 1.0f / r;
        const float sr0 = valid;
        const float sr1 = valid * rx * inv_r;
        const float sr2 = valid * ry * inv_r;
        const float sr3 = valid * rz * inv_r;

        const float* Arow = &A_sh[tk * 48];
        float dfc = 0.0f, dx = 0.0f;
        float tA1 = 0.0f, tA2 = 0.0f, tA3 = 0.0f;
        float tpm1 = 1.0f, tpm2 = 0.0f;
#pragma unroll
        for (int j = 0; j < BETA; ++j) {
            const float a0 = Arow[j*4+0], a1 = Arow[j*4+1];
            const float a2 = Arow[j*4+2], a3 = Arow[j*4+3];
            const float cjj = a0*sr0 + a1*sr1 + a2*sr2 + a3*sr3;
            dfc = fmaf(T[j], cjj, dfc);
            tA1 = fmaf(T[j], a1, tA1);
            tA2 = fmaf(T[j], a2, tA2);
            tA3 = fmaf(T[j], a3, tA3);
            if (j == 1) {
                dx = cjj;
            } else if (j >= 2) {
                const float tp = 2.0f * T[j-1] + 2.0f * x * tpm1 - tpm2;
                dx = fmaf(cjj, tp, dx);
                tpm2 = tpm1; tpm1 = tp;
            }
        }
        const float dsr1 = fc * tA1, dsr2 = fc * tA2, dsr3 = fc * tA3;

        float dfcdr = 0.0f;
        if (uraw > 0.0f && uraw < 1.0f)
            dfcdr = -0.5f * PI_F * sinf(PI_F * u) * valid / LSPAN;
        const float drt = (fc * dx) * (2.0f / LSPAN) + dfc * dfcdr;
        const float Sdot = dsr1 * rx + dsr2 * ry + dsr3 * rz;
        const float common = drt * inv_r - valid * Sdot * inv_r * inv_r * inv_r;
        const float gx = common * rx + valid * dsr1 * inv_r;
        const float gy = common * ry + valid * dsr2 * inv_r;
        const float gz = common * rz + valid * dsr3 * inv_r;

        if (lni >= 0) {
            atomicAdd(&fcontrib[lni * 3 + 0], -gx);
            atomicAdd(&fcontrib[lni * 3 + 1], -gy);
            atomicAdd(&fcontrib[lni * 3 + 2], -gz);
        }

        {
            float s0 = gx, s1 = gy, s2 = gz;
#pragma unroll
            for (int m = 32; m >= 1; m >>= 1) {
                s0 += __shfl_xor(s0, m);
                s1 += __shfl_xor(s1, m);
                s2 += __shfl_xor(s2, m);
            }
            if (lane == 0) {
                red12[0 * 4 + wid] = s0;
                red12[1 * 4 + wid] = s1;
                red12[2 * 4 + wid] = s2;
            }
        }
        __syncthreads();
        if (tid < 3) {
            const float v = red12[tid*4+0] + red12[tid*4+1] + red12[tid*4+2] + red12[tid*4+3];
            atomicAdd(&fcontrib[n * 3 + tid], v);
        }

        vv0 = fmaf(-rx, gx, vv0); vv1 = fmaf(-rx, gy, vv1); vv2 = fmaf(-rx, gz, vv2);
        vv3 = fmaf(-ry, gx, vv3); vv4 = fmaf(-ry, gy, vv4); vv5 = fmaf(-ry, gz, vv5);
        vv6 = fmaf(-rz, gx, vv6); vv7 = fmaf(-rz, gy, vv7); vv8 = fmaf(-rz, gz, vv8);
    }

    {
        float vals[9] = {vv0,vv1,vv2,vv3,vv4,vv5,vv6,vv7,vv8};
        __syncthreads();
#pragma unroll
        for (int i = 0; i < 9; ++i) {
            float v = vals[i];
#pragma unroll
            for (int m = 32; m >= 1; m >>= 1) v += __shfl_xor(v, m);
            if (lane == 0) red12[i * 4 + wid] = v;
        }
        __syncthreads();
        if (tid < 9)
            vir_ws[(size_t)g * 9 + tid] = red12[tid*4+0] + red12[tid*4+1]
                                        + red12[tid*4+2] + red12[tid*4+3];
    }

    __syncthreads();
    {
        float4* dst = reinterpret_cast<float4*>(contrib_ws + (size_t)g * (N_ * 3));
        const float4* src = reinterpret_cast<const float4*>(fcontrib);
        for (int i = tid; i < (N_ * 3) / 4; i += 256) dst[i] = src[i];
    }
}

// ---------------- K3R: sliced column-sum of contrib ----------------
__global__ __launch_bounds__(256) void k3_reduce(
    const float* __restrict__ contrib_ws,
    float* __restrict__ partial_ws)
{
    const int x  = blockIdx.x;          // SL*B_*3 blocks
    const int ch = x % 3;
    const int bb = (x / 3) % B_;
    const int s  = x / (3 * B_);
    const int c4 = ch * 256 + threadIdx.x;
    const int rows = (NG3 / B_) / SL;   // 128/8 = 16
    const int g0 = bb * (NG3 / B_) + s * rows;

    const float4* src = reinterpret_cast<const float4*>(contrib_ws);
    float4 a0 = {0,0,0,0}, a1 = {0,0,0,0};
    for (int r = 0; r < rows; r += 2) {
        const float4 v0 = src[(size_t)(g0 + r)     * 768 + c4];
        const float4 v1 = src[(size_t)(g0 + r + 1) * 768 + c4];
        a0.x += v0.x; a0.y += v0.y; a0.z += v0.z; a0.w += v0.w;
        a1.x += v1.x; a1.y += v1.y; a1.z += v1.z; a1.w += v1.w;
    }
    const float4 res = {a0.x + a1.x, a0.y + a1.y, a0.z + a1.z, a0.w + a1.w};
    reinterpret_cast<float4*>(partial_ws)[(size_t)(s * B_ + bb) * 768 + c4] = res;
}

// ---------------- K4: finalize Force, Etot, Virial ----------------
__global__ __launch_bounds__(256) void k4_final(
    const float* __restrict__ vir_ws,
    const float* __restrict__ partial_ws,
    float* __restrict__ out)
{
    __shared__ float red[10 * 4];
    const int tid  = threadIdx.x;
    const int lane = tid & 63;
    const int wid  = tid >> 6;
    const int b = blockIdx.x;

    for (int i = tid; i < N_ * 3; i += 256) {
        float f = 0.0f;
#pragma unroll
        for (int s = 0; s < SL; ++s) f += partial_ws[(size_t)(s * B_ + b) * (N_ * 3) + i];
        out[F_OFF + (size_t)b * (N_ * 3) + i] = f;
    }

    float vals[10];
#pragma unroll
    for (int i = 0; i < 10; ++i) vals[i] = 0.0f;
    for (int n = tid; n < N_; n += 256) vals[0] += out[EI_OFF + b * N_ + n];
    if (tid < NG3 / B_) {               // 128 virial rows per batch
        const float* vp = vir_ws + ((size_t)b * (NG3 / B_) + tid) * 9;
#pragma unroll
        for (int j = 0; j < 9; ++j) vals[1 + j] = vp[j];
    }
#pragma unroll
    for (int i = 0; i < 10; ++i) {
        float v = vals[i];
#pragma unroll
        for (int m = 32; m >= 1; m >>= 1) v += __shfl_xor(v, m);
        if (lane == 0) red[i * 4 + wid] = v;
    }
    __syncthreads();
    if (tid < 10) {
        const float v = red[tid*4+0] + red[tid*4+1] + red[tid*4+2] + red[tid*4+3];
        if (tid == 0) out[b] = v;
        else          out[V_OFF + b * 9 + (tid - 1)] = v;
    }
}

extern "C" void kernel_launch(void* const* d_in, const int* in_sizes, int n_in,
                              void* d_out, int out_size, void* d_ws, size_t ws_size,
                              hipStream_t stream) {
    float* out = (float*)d_out;
    float* ws  = (float*)d_ws;
    float* feat_ws    = ws + WS_FEAT;
    float* R_ws       = ws + WS_R;
    float* A_ws       = ws + WS_A;
    float* vir_ws     = ws + WS_VIR;
    float* contrib_ws = ws + WS_CONTRIB;
    float* partial_ws = ws + WS_PARTIAL;
    int*   sites_ws   = (int*)(ws + WS_SITES);

    const int*   list_neigh = (const int*)d_in[0];
    const int*   type_map   = (const int*)d_in[1];
    const float* imagedr    = (const float*)d_in[3];
    const float* c_param    = (const float*)d_in[6];
    const float* scale      = (const float*)d_in[7];
    const float* W0 = (const float*)d_in[8];
    const float* b0 = (const float*)d_in[9];
    const float* W1 = (const float*)d_in[10];
    const float* b1 = (const float*)d_in[11];
    const float* W2 = (const float*)d_in[12];
    const float* b2 = (const float*)d_in[13];
    const float* eshift = (const float*)d_in[14];

    k0_sort<<<1, 1024, 0, stream>>>(type_map, sites_ws);
    k1_embed<<<B_ * N_, 256, 0, stream>>>(list_neigh, type_map, imagedr, c_param,
                                          scale, feat_ws, R_ws);
    k2_mlp<<<NTILE, 256, 0, stream>>>(type_map, scale, W0, b0, W1, b1, W2, b2,
                                      eshift, feat_ws, feat_ws /*alias dfeat*/, out,
                                      sites_ws);
    k3a_prep<<<B_ * N_ / 2, 256, 0, stream>>>(type_map, c_param, feat_ws /*dfeat*/,
                                              R_ws, A_ws);
    k3_bwd<<<NG3, 256, 0, stream>>>(list_neigh, imagedr, A_ws, contrib_ws, vir_ws);
    k3_reduce<<<SL * B_ * 3, 256, 0, stream>>>(contrib_ws, partial_ws);
    k4_final<<<B_, 256, 0, stream>>>(vir_ws, partial_ws, out);
}

// Round 13
// 197.772 us; speedup vs baseline: 1.1863x; 1.0228x over previous
//
#include <hip/hip_runtime.h>
#include <math.h>

#define RMINF  0.5f
#define LSPAN  5.5f          // RC - RMIN
constexpr int BETA = 12, M1 = 24, M2 = 6;
constexpr int B_ = 4, N_ = 1024, NT_ = 2, MN_ = 128;
constexpr int K_ = NT_ * MN_;        // 256
constexpr int NFEAT = M1 * M2;       // 144
constexpr int HID = 128;
constexpr float PI_F = 3.14159265358979323846f;

// Output layout: Etot(4) | Ei(4096) | Force(4*1024*3) | Virial(36)
constexpr int EI_OFF = B_;                  // 4
constexpr int F_OFF  = B_ + B_ * N_;        // 4100
constexpr int V_OFF  = F_OFF + B_ * N_ * 3; // 16388

constexpr int G3 = 8;                  // source atoms per k3 block
constexpr int NG3 = B_ * N_ / G3;      // 512 k3 blocks
constexpr int SL = 8;                  // reduce slices
constexpr int NTILE = 258;             // site list tiles of 4 (1032 entries)
constexpr int NT2 = 516;               // k2 tiles of 2 sites

// Workspace layout (floats)
constexpr size_t WS_FEAT    = 0;                                 // 4096*144
constexpr size_t WS_R       = (size_t)B_ * N_ * NFEAT;           // 4096*96
constexpr size_t WS_A       = WS_R + (size_t)B_ * N_ * 96;       // 4096*96
constexpr size_t WS_VIR     = WS_A + (size_t)B_ * N_ * 96;       // 512*9
constexpr size_t WS_CONTRIB = WS_VIR + (size_t)NG3 * 9;          // 512*3072
constexpr size_t WS_PARTIAL = WS_CONTRIB + (size_t)NG3 * N_ * 3; // 8*4*3072
constexpr size_t WS_SITES   = WS_PARTIAL + (size_t)SL * B_ * N_ * 3; // 1032 ints

// Journal:
// - (256,4) launch_bounds -> 64 VGPR -> scratch spill -> 2 GB HBM (r4/r6).
// - r8: spill fixed. r9: algebraic A/M contraction; k2 4-acc: 50us.
// - r10: occupancy without reuse -> 88us. r11: LDS-staged weights 61us
//   (5 ds per 4 FMA, LDS-issue bound).
// - r12: 16-atom tiles: ratio 3:8 but LDS 61KB + grid 258 -> 4 waves/CU,
//   78us. Ratio/LDS/grid must be balanced together.
// - r13: 8-atom tiles (516 blocks), reused act buffer (~32KB LDS),
//   2 ds per 4 FMA, 8-12 waves/CU.

// ---------------- K0: type-sorted, 4-padded site list ----------------
__global__ void k0_sort(const int* __restrict__ type_map, int* __restrict__ sites)
{
    __shared__ int counts[2];
    __shared__ int base[2];
    __shared__ int cursor[2];
    const int tid = threadIdx.x;
    if (tid < 2) { counts[tid] = 0; cursor[tid] = 0; }
    for (int i = tid; i < NTILE * 4; i += 1024) sites[i] = -1;
    __syncthreads();
    int myt = -1;
    if (tid < N_) { myt = type_map[tid]; atomicAdd(&counts[myt], 1); }
    __syncthreads();
    if (tid == 0) { base[0] = 0; base[1] = ((counts[0] + 3) >> 2) << 2; }
    __syncthreads();
    if (tid < N_) {
        const int p = atomicAdd(&cursor[myt], 1);
        sites[base[myt] + p] = tid;
    }
}

// ---------------- K1: embedding forward -> feat, R ----------------
__global__ __launch_bounds__(256) void k1_embed(
    const int*   __restrict__ list_neigh,
    const int*   __restrict__ type_map,
    const float* __restrict__ imagedr,
    const float* __restrict__ c_param,
    const float* __restrict__ scale,
    float* __restrict__ feat_ws,
    float* __restrict__ R_ws)
{
    __shared__ float c_sh[NT_ * M1 * BETA];   // [tk][f][j] 576
    __shared__ float p_sh[K_][13];            // fc*T_j, padded
    __shared__ float sr_sh[K_][5];
    __shared__ float Mpart[2][96];            // [sub][tk*48 + j*4 + c]
    __shared__ float R_sh[96];

    const int tid = threadIdx.x;
    const int bn = blockIdx.x;
    const int n  = bn % N_;
    const int tn = type_map[n];

    for (int i = tid; i < NT_ * M1 * BETA; i += 256)
        c_sh[i] = c_param[tn * (NT_ * M1 * BETA) + i];

    const int k = tid;
    const int lni = list_neigh[(size_t)bn * K_ + k];
    const float valid = (lni >= 0) ? 1.0f : 0.0f;

    const float4 dr4 = reinterpret_cast<const float4*>(imagedr)[(size_t)bn * K_ + k];
    const float rx = dr4.y, ry = dr4.z, rz = dr4.w;
    const float r  = sqrtf(rx*rx + ry*ry + rz*rz + 1e-12f);
    const float uraw = (r - RMINF) / LSPAN;
    const float u  = fminf(fmaxf(uraw, 0.0f), 1.0f);
    const float fc = 0.5f * (cosf(PI_F * u) + 1.0f) * valid;
    const float x  = 2.0f * (r - RMINF) / LSPAN - 1.0f;

    float T[BETA];
    T[0] = 1.0f; T[1] = x;
#pragma unroll
    for (int j = 2; j < BETA; ++j) T[j] = 2.0f * x * T[j-1] - T[j-2];

    const float inv_r = 1.0f / r;
    sr_sh[k][0] = valid;
    sr_sh[k][1] = valid * rx * inv_r;
    sr_sh[k][2] = valid * ry * inv_r;
    sr_sh[k][3] = valid * rz * inv_r;
#pragma unroll
    for (int j = 0; j < BETA; ++j) p_sh[k][j] = fc * T[j];
    __syncthreads();

    if (tid < 192) {
        const int sub = tid / 96, idx = tid % 96;
        const int tk = idx / 48, rem = idx % 48;
        const int j = rem >> 2, cc = rem & 3;
        const int k0 = tk * 128 + sub * 64;
        float a0 = 0.0f, a1 = 0.0f;
        for (int kk = k0; kk < k0 + 64; kk += 2) {
            a0 = fmaf(p_sh[kk][j],   sr_sh[kk][cc],   a0);
            a1 = fmaf(p_sh[kk+1][j], sr_sh[kk+1][cc], a1);
        }
        Mpart[sub][idx] = a0 + a1;
    }
    __syncthreads();

    if (tid < 96) {
        const int f = tid >> 2, cc = tid & 3;
        float acc = 0.0f;
#pragma unroll
        for (int tk = 0; tk < NT_; ++tk) {
#pragma unroll
            for (int j = 0; j < BETA; ++j) {
                const float m = Mpart[0][tk*48 + j*4 + cc] + Mpart[1][tk*48 + j*4 + cc];
                acc = fmaf(c_sh[tk*288 + f*12 + j], m, acc);
            }
        }
        const float v = acc * (1.0f / MN_);
        R_sh[tid] = v;
        R_ws[(size_t)bn * 96 + tid] = v;
    }
    __syncthreads();
    if (tid < NFEAT) {
        const int f = tid / 6, g = tid % 6;
        float acc = 0.0f;
#pragma unroll
        for (int c = 0; c < 4; ++c) acc += R_sh[f * 4 + c] * R_sh[g * 4 + c];
        feat_ws[(size_t)bn * NFEAT + tid] = acc * scale[tid];
    }
}

// ---------------- K2: MLP fwd+bwd, 8 same-type atoms per block -----------
// Tile = 2 sites x 4 batches; 256 thr = (col c 0..127) x (half = site).
// Each thread: 4 atoms (its site's 4 batches), 4 accs.
// Activations in LDS [row][8] stride 12 (float4-aligned); one buffer
// reused h -> dz1 -> dz0. Weights chunk-staged (stride 145).
__global__ __launch_bounds__(256) void k2_mlp(
    const int*   __restrict__ type_map,
    const float* __restrict__ scale,
    const float* __restrict__ W0,
    const float* __restrict__ b0,
    const float* __restrict__ W1,
    const float* __restrict__ b1,
    const float* __restrict__ W2,
    const float* __restrict__ b2,
    const float* __restrict__ eshift,
    const float* __restrict__ feat_ws,
    float* __restrict__ dfeat_ws,     // may alias feat_ws
    float* __restrict__ out,
    const int* __restrict__ sites)
{
    constexpr int WSR = 145;
    constexpr int AP  = 12;               // atom-dim pad
    __shared__ float feat2[NFEAT * AP];   // 6.9 KB
    __shared__ float act[HID * AP];       // 6.1 KB: h -> dz1 -> dz0
    __shared__ float wbuf[32 * WSR];      // 18.6 KB
    __shared__ float red[4][4];           // [wid][bb]
    __shared__ int   s_sh[2];

    const int tid  = threadIdx.x;
    const int c    = tid & 127;
    const int half = tid >> 7;
    const int lane = tid & 63;
    const int wid  = tid >> 6;

    if (tid < 2) s_sh[tid] = sites[blockIdx.x * 2 + tid];
    __syncthreads();
    const int s0 = s_sh[0], s1 = s_sh[1];
    const int sv = (s0 >= 0) ? s0 : s1;
    if (sv < 0) return;
    const int tn  = type_map[sv];
    const int smy = (half == 0) ? s0 : s1;

    // stage feat2[f][r], r = si*4+bb
    for (int r = 0; r < 8; ++r) {
        const int si = r >> 2, bb = r & 3;
        const int s = (si == 0) ? s0 : s1;
        if (tid < NFEAT)
            feat2[tid * AP + r] = (s >= 0)
                ? feat_ws[((size_t)bb * N_ + s) * NFEAT + tid] : 0.0f;
    }

    const float* W0t = W0 + (size_t)tn * NFEAT * HID;
    const float* W1t = W1 + (size_t)tn * HID * HID;

    // ---- layer 0 ----
    float acc[4];
    {
        const float bias = b0[tn * HID + c];
        acc[0] = acc[1] = acc[2] = acc[3] = bias;
    }
    for (int ch = 0; ch < NFEAT; ch += 32) {
        const int rows = (NFEAT - ch) < 32 ? (NFEAT - ch) : 32;
        __syncthreads();                   // wbuf free (+ feat2 staged, 1st it)
        for (int i = tid; i < rows * 128; i += 256) {
            const int f = i >> 7, cc = i & 127;
            wbuf[f * WSR + cc] = W0t[(size_t)(ch + f) * HID + cc];
        }
        __syncthreads();
#pragma unroll 4
        for (int f0 = 0; f0 < rows; ++f0) {
            const float w = wbuf[f0 * WSR + c];
            const float4 v = *reinterpret_cast<const float4*>(&feat2[(ch+f0)*AP + half*4]);
            acc[0] = fmaf(v.x, w, acc[0]); acc[1] = fmaf(v.y, w, acc[1]);
            acc[2] = fmaf(v.z, w, acc[2]); acc[3] = fmaf(v.w, w, acc[3]);
        }
    }
    float hv[4];
#pragma unroll
    for (int a = 0; a < 4; ++a) hv[a] = tanhf(acc[a]);
    *reinterpret_cast<float4*>(&act[c * AP + half * 4]) =
        make_float4(hv[0], hv[1], hv[2], hv[3]);

    // ---- layer 1 ----
    {
        const float bias = b1[tn * HID + c];
        acc[0] = acc[1] = acc[2] = acc[3] = bias;
    }
    for (int ch = 0; ch < HID; ch += 32) {
        __syncthreads();                   // act(h) published / wbuf free
        for (int i = tid; i < 32 * 128; i += 256) {
            const int g = i >> 7, cc = i & 127;
            wbuf[g * WSR + cc] = W1t[(size_t)(ch + g) * HID + cc];
        }
        __syncthreads();
#pragma unroll 4
        for (int g0 = 0; g0 < 32; ++g0) {
            const float w = wbuf[g0 * WSR + c];
            const float4 v = *reinterpret_cast<const float4*>(&act[(ch+g0)*AP + half*4]);
            acc[0] = fmaf(v.x, w, acc[0]); acc[1] = fmaf(v.y, w, acc[1]);
            acc[2] = fmaf(v.z, w, acc[2]); acc[3] = fmaf(v.w, w, acc[3]);
        }
    }

    const float w2c = W2[tn * HID + c];
    float dz1v[4], ei[4];
#pragma unroll
    for (int a = 0; a < 4; ++a) {
        const float t1 = tanhf(acc[a]);
        dz1v[a] = w2c * (1.0f - t1 * t1);
        ei[a] = (t1 + hv[a]) * w2c;
    }
#pragma unroll
    for (int a = 0; a < 4; ++a) {
        float v = ei[a];
#pragma unroll
        for (int m = 32; m >= 1; m >>= 1) v += __shfl_xor(v, m);
        if (lane == 0) red[wid][a] = v;
    }
    __syncthreads();                       // all layer-1 reads of act done
    if (tid < 8) {
        const int si = tid >> 2, bb = tid & 3;
        const int s = (si == 0) ? s0 : s1;
        if (s >= 0)
            out[EI_OFF + (size_t)bb * N_ + s] =
                red[si*2][bb] + red[si*2+1][bb] + b2[tn] + eshift[tn];
    }
    *reinterpret_cast<float4*>(&act[c * AP + half * 4]) =
        make_float4(dz1v[0], dz1v[1], dz1v[2], dz1v[3]);

    // ---- dz0 = (w2 + W1^T-chunks . dz1) * (1-h^2) ----
    acc[0] = acc[1] = acc[2] = acc[3] = w2c;
    for (int ch = 0; ch < HID; ch += 32) {
        __syncthreads();                   // act(dz1) published / wbuf free
        for (int i = tid; i < 32 * 128; i += 256) {
            const int j = i & 31, hh = i >> 5;
            wbuf[j * WSR + hh] = W1t[(size_t)hh * HID + ch + j];
        }
        __syncthreads();
#pragma unroll 4
        for (int j = 0; j < 32; ++j) {
            const float w = wbuf[j * WSR + c];     // = W1[c][ch+j]
            const float4 v = *reinterpret_cast<const float4*>(&act[(ch+j)*AP + half*4]);
            acc[0] = fmaf(v.x, w, acc[0]); acc[1] = fmaf(v.y, w, acc[1]);
            acc[2] = fmaf(v.z, w, acc[2]); acc[3] = fmaf(v.w, w, acc[3]);
        }
    }
    float dz0v[4];
#pragma unroll
    for (int a = 0; a < 4; ++a) dz0v[a] = acc[a] * (1.0f - hv[a] * hv[a]);
    __syncthreads();                       // all dz0-phase reads of act done
    *reinterpret_cast<float4*>(&act[c * AP + half * 4]) =
        make_float4(dz0v[0], dz0v[1], dz0v[2], dz0v[3]);

    // ---- dfeat = scale * (W0^T-chunks . dz0) ----
    float d0[4] = {0,0,0,0};
    float d1[4] = {0,0,0,0};
    const int c2 = (c < NFEAT - HID) ? (HID + c) : HID;   // clamped
    for (int ch = 0; ch < HID; ch += 32) {
        __syncthreads();                   // act(dz0) published / wbuf free
        for (int i = tid; i < 32 * NFEAT; i += 256) {     // 4608 = 18*256
            const int j = i & 31, f = i >> 5;
            wbuf[j * WSR + f] = W0t[(size_t)f * HID + ch + j];
        }
        __syncthreads();
#pragma unroll 4
        for (int j = 0; j < 32; ++j) {
            const float w  = wbuf[j * WSR + c];    // = W0[c][ch+j]
            const float w2 = wbuf[j * WSR + c2];   // = W0[128+c][ch+j] (c<16)
            const float4 v = *reinterpret_cast<const float4*>(&act[(ch+j)*AP + half*4]);
            d0[0] = fmaf(v.x, w, d0[0]); d0[1] = fmaf(v.y, w, d0[1]);
            d0[2] = fmaf(v.z, w, d0[2]); d0[3] = fmaf(v.w, w, d0[3]);
            d1[0] = fmaf(v.x, w2, d1[0]); d1[1] = fmaf(v.y, w2, d1[1]);
            d1[2] = fmaf(v.z, w2, d1[2]); d1[3] = fmaf(v.w, w2, d1[3]);
        }
    }
    if (smy >= 0) {
        const float sc  = scale[c];
#pragma unroll
        for (int a = 0; a < 4; ++a)
            dfeat_ws[((size_t)a * N_ + smy) * NFEAT + c] = d0[a] * sc;
        if (c < NFEAT - HID) {
            const float sc2 = scale[HID + c];
#pragma unroll
            for (int a = 0; a < 4; ++a)
                dfeat_ws[((size_t)a * N_ + smy) * NFEAT + HID + c] = d1[a] * sc2;
        }
    }
}

// ---------------- K3a: per-atom dR + A precompute ----------------
__global__ __launch_bounds__(256) void k3a_prep(
    const int*   __restrict__ type_map,
    const float* __restrict__ c_param,
    const float* __restrict__ dfeat_ws,
    const float* __restrict__ R_ws,
    float* __restrict__ A_ws)
{
    __shared__ float call[NT_ * NT_ * M1 * BETA];   // 1152: whole c_param
    __shared__ float df[2][NFEAT];
    __shared__ float R2[2][96];
    __shared__ float dR2[2][96];

    const int tid = threadIdx.x;
    const int bn0 = blockIdx.x * 2;

    for (int i = tid; i < NT_ * NT_ * M1 * BETA; i += 256) call[i] = c_param[i];
    for (int i = tid; i < 2 * NFEAT; i += 256)
        df[i / NFEAT][i % NFEAT] = dfeat_ws[(size_t)(bn0 + i / NFEAT) * NFEAT + i % NFEAT];
    for (int i = tid; i < 2 * 96; i += 256)
        R2[i / 96][i % 96] = R_ws[(size_t)(bn0 + i / 96) * 96 + i % 96];
    __syncthreads();

    if (tid < 192) {
        const int at = tid / 96, idx = tid % 96;
        const int p = idx >> 2, cc = idx & 3;
        float a = 0.0f;
#pragma unroll
        for (int gg = 0; gg < M2; ++gg) a += df[at][p * 6 + gg] * R2[at][gg * 4 + cc];
        if (p < M2) {
            for (int f = 0; f < M1; ++f) a += df[at][f * 6 + p] * R2[at][f * 4 + cc];
        }
        dR2[at][idx] = a * (1.0f / MN_);
    }
    __syncthreads();
    if (tid < 192) {
        const int at = tid / 96, idx = tid % 96;
        const int tkk = idx / 48, rem = idx % 48;
        const int j = rem >> 2, cc = rem & 3;
        const int tnat = type_map[(bn0 + at) & (N_ - 1)];
        float a = 0.0f;
#pragma unroll
        for (int f = 0; f < M1; ++f)
            a = fmaf(call[tnat * 576 + tkk * 288 + f * 12 + j], dR2[at][f * 4 + cc], a);
        A_ws[(size_t)(bn0 + at) * 96 + idx] = a;
    }
}

// ---------------- K3: neighbor backward, G3 atoms/block, LDS force image --
__global__ __launch_bounds__(256) void k3_bwd(
    const int*   __restrict__ list_neigh,
    const float* __restrict__ imagedr,
    const float* __restrict__ A_ws,
    float* __restrict__ contrib_ws,
    float* __restrict__ vir_ws)
{
    __shared__ float fcontrib[N_ * 3];      // 12 KB force image
    __shared__ float A_sh[96];
    __shared__ float red12[12 * 4];

    const int tid  = threadIdx.x;
    const int lane = tid & 63;
    const int wid  = tid >> 6;
    const int g  = blockIdx.x;              // 0..NG3-1
    const int tk = tid >> 7;

    for (int i = tid; i < N_ * 3; i += 256) fcontrib[i] = 0.0f;

    float vv0=0.f,vv1=0.f,vv2=0.f,vv3=0.f,vv4=0.f,vv5=0.f,vv6=0.f,vv7=0.f,vv8=0.f;

    for (int aa = 0; aa < G3; ++aa) {
        const int bn = g * G3 + aa;
        const int n  = bn & (N_ - 1);

        __syncthreads();                    // A_sh free / fcontrib zero done
        if (tid < 96) A_sh[tid] = A_ws[(size_t)bn * 96 + tid];
        __syncthreads();

        const int lni = list_neigh[(size_t)bn * K_ + tid];
        const float valid = (lni >= 0) ? 1.0f : 0.0f;
        const float4 dr4 = reinterpret_cast<const float4*>(imagedr)[(size_t)bn * K_ + tid];
        const float rx = dr4.y, ry = dr4.z, rz = dr4.w;
        const float r  = sqrtf(rx*rx + ry*ry + rz*rz + 1e-12f);
        const float uraw = (r - RMINF) / LSPAN;
        const float u  = fminf(fmaxf(uraw, 0.0f), 1.0f);
        const float fc = 0.5f * (cosf(PI_F * u) + 1.0f) * valid;
        const float x  = 2.0f * (r - RMINF) / LSPAN - 1.0f;

        float T[BETA];
        T[0] = 1.0f; T[1] = x;
#pragma unroll
        for (int j = 2; j < BETA; ++j) T[j] = 2.0f * x * T[j-1] - T[j-2];

        const float inv_r = 1.0f / r;
        const float sr0 = valid;
        const float sr1 = valid * rx * inv_r;
        const float sr2 = valid * ry * inv_r;
        const float sr3 = valid * rz * inv_r;

        const float* Arow = &A_sh[tk * 48];
        float dfc = 0.0f, dx = 0.0f;
        float tA1 = 0.0f, tA2 = 0.0f, tA3 = 0.0f;
        float tpm1 = 1.0f, tpm2 = 0.0f;
#pragma unroll
        for (int j = 0; j < BETA; ++j) {
            const float a0 = Arow[j*4+0], a1 = Arow[j*4+1];
            const float a2 = Arow[j*4+2], a3 = Arow[j*4+3];
            const float cjj = a0*sr0 + a1*sr1 + a2*sr2 + a3*sr3;
            dfc = fmaf(T[j], cjj, dfc);
            tA1 = fmaf(T[j], a1, tA1);
            tA2 = fmaf(T[j], a2, tA2);
            tA3 = fmaf(T[j], a3, tA3);
            if (j == 1) {
                dx = cjj;
            } else if (j >= 2) {
                const float tp = 2.0f * T[j-1] + 2.0f * x * tpm1 - tpm2;
                dx = fmaf(cjj, tp, dx);
                tpm2 = tpm1; tpm1 = tp;
            }
        }
        const float dsr1 = fc * tA1, dsr2 = fc * tA2, dsr3 = fc * tA3;

        float dfcdr = 0.0f;
        if (uraw > 0.0f && uraw < 1.0f)
            dfcdr = -0.5f * PI_F * sinf(PI_F * u) * valid / LSPAN;
        const float drt = (fc * dx) * (2.0f / LSPAN) + dfc * dfcdr;
        const float Sdot = dsr1 * rx + dsr2 * ry + dsr3 * rz;
        const float common = drt * inv_r - valid * Sdot * inv_r * inv_r * inv_r;
        const float gx = common * rx + valid * dsr1 * inv_r;
        const float gy = common * ry + valid * dsr2 * inv_r;
        const float gz = common * rz + valid * dsr3 * inv_r;

        if (lni >= 0) {
            atomicAdd(&fcontrib[lni * 3 + 0], -gx);
            atomicAdd(&fcontrib[lni * 3 + 1], -gy);
            atomicAdd(&fcontrib[lni * 3 + 2], -gz);
        }

        {
            float s0 = gx, s1 = gy, s2 = gz;
#pragma unroll
            for (int m = 32; m >= 1; m >>= 1) {
                s0 += __shfl_xor(s0, m);
                s1 += __shfl_xor(s1, m);
                s2 += __shfl_xor(s2, m);
            }
            if (lane == 0) {
                red12[0 * 4 + wid] = s0;
                red12[1 * 4 + wid] = s1;
                red12[2 * 4 + wid] = s2;
            }
        }
        __syncthreads();
        if (tid < 3) {
            const float v = red12[tid*4+0] + red12[tid*4+1] + red12[tid*4+2] + red12[tid*4+3];
            atomicAdd(&fcontrib[n * 3 + tid], v);
        }

        vv0 = fmaf(-rx, gx, vv0); vv1 = fmaf(-rx, gy, vv1); vv2 = fmaf(-rx, gz, vv2);
        vv3 = fmaf(-ry, gx, vv3); vv4 = fmaf(-ry, gy, vv4); vv5 = fmaf(-ry, gz, vv5);
        vv6 = fmaf(-rz, gx, vv6); vv7 = fmaf(-rz, gy, vv7); vv8 = fmaf(-rz, gz, vv8);
    }

    {
        float vals[9] = {vv0,vv1,vv2,vv3,vv4,vv5,vv6,vv7,vv8};
        __syncthreads();
#pragma unroll
        for (int i = 0; i < 9; ++i) {
            float v = vals[i];
#pragma unroll
            for (int m = 32; m >= 1; m >>= 1) v += __shfl_xor(v, m);
            if (lane == 0) red12[i * 4 + wid] = v;
        }
        __syncthreads();
        if (tid < 9)
            vir_ws[(size_t)g * 9 + tid] = red12[tid*4+0] + red12[tid*4+1]
                                        + red12[tid*4+2] + red12[tid*4+3];
    }

    __syncthreads();
    {
        float4* dst = reinterpret_cast<float4*>(contrib_ws + (size_t)g * (N_ * 3));
        const float4* src = reinterpret_cast<const float4*>(fcontrib);
        for (int i = tid; i < (N_ * 3) / 4; i += 256) dst[i] = src[i];
    }
}

// ---------------- K3R: sliced column-sum of contrib ----------------
__global__ __launch_bounds__(256) void k3_reduce(
    const float* __restrict__ contrib_ws,
    float* __restrict__ partial_ws)
{
    const int x  = blockIdx.x;          // SL*B_*3 blocks
    const int ch = x % 3;
    const int bb = (x / 3) % B_;
    const int s  = x / (3 * B_);
    const int c4 = ch * 256 + threadIdx.x;
    const int rows = (NG3 / B_) / SL;   // 128/8 = 16
    const int g0 = bb * (NG3 / B_) + s * rows;

    const float4* src = reinterpret_cast<const float4*>(contrib_ws);
    float4 a0 = {0,0,0,0}, a1 = {0,0,0,0};
    for (int r = 0; r < rows; r += 2) {
        const float4 v0 = src[(size_t)(g0 + r)     * 768 + c4];
        const float4 v1 = src[(size_t)(g0 + r + 1) * 768 + c4];
        a0.x += v0.x; a0.y += v0.y; a0.z += v0.z; a0.w += v0.w;
        a1.x += v1.x; a1.y += v1.y; a1.z += v1.z; a1.w += v1.w;
    }
    const float4 res = {a0.x + a1.x, a0.y + a1.y, a0.z + a1.z, a0.w + a1.w};
    reinterpret_cast<float4*>(partial_ws)[(size_t)(s * B_ + bb) * 768 + c4] = res;
}

// ---------------- K4: finalize Force, Etot, Virial ----------------
__global__ __launch_bounds__(256) void k4_final(
    const float* __restrict__ vir_ws,
    const float* __restrict__ partial_ws,
    float* __restrict__ out)
{
    __shared__ float red[10 * 4];
    const int tid  = threadIdx.x;
    const int lane = tid & 63;
    const int wid  = tid >> 6;
    const int b = blockIdx.x;

    for (int i = tid; i < N_ * 3; i += 256) {
        float f = 0.0f;
#pragma unroll
        for (int s = 0; s < SL; ++s) f += partial_ws[(size_t)(s * B_ + b) * (N_ * 3) + i];
        out[F_OFF + (size_t)b * (N_ * 3) + i] = f;
    }

    float vals[10];
#pragma unroll
    for (int i = 0; i < 10; ++i) vals[i] = 0.0f;
    for (int n = tid; n < N_; n += 256) vals[0] += out[EI_OFF + b * N_ + n];
    if (tid < NG3 / B_) {               // 128 virial rows per batch
        const float* vp = vir_ws + ((size_t)b * (NG3 / B_) + tid) * 9;
#pragma unroll
        for (int j = 0; j < 9; ++j) vals[1 + j] = vp[j];
    }
#pragma unroll
    for (int i = 0; i < 10; ++i) {
        float v = vals[i];
#pragma unroll
        for (int m = 32; m >= 1; m >>= 1) v += __shfl_xor(v, m);
        if (lane == 0) red[i * 4 + wid] = v;
    }
    __syncthreads();
    if (tid < 10) {
        const float v = red[tid*4+0] + red[tid*4+1] + red[tid*4+2] + red[tid*4+3];
        if (tid == 0) out[b] = v;
        else          out[V_OFF + b * 9 + (tid - 1)] = v;
    }
}

extern "C" void kernel_launch(void* const* d_in, const int* in_sizes, int n_in,
                              void* d_out, int out_size, void* d_ws, size_t ws_size,
                              hipStream_t stream) {
    float* out = (float*)d_out;
    float* ws  = (float*)d_ws;
    float* feat_ws    = ws + WS_FEAT;
    float* R_ws       = ws + WS_R;
    float* A_ws       = ws + WS_A;
    float* vir_ws     = ws + WS_VIR;
    float* contrib_ws = ws + WS_CONTRIB;
    float* partial_ws = ws + WS_PARTIAL;
    int*   sites_ws   = (int*)(ws + WS_SITES);

    const int*   list_neigh = (const int*)d_in[0];
    const int*   type_map   = (const int*)d_in[1];
    const float* imagedr    = (const float*)d_in[3];
    const float* c_param    = (const float*)d_in[6];
    const float* scale      = (const float*)d_in[7];
    const float* W0 = (const float*)d_in[8];
    const float* b0 = (const float*)d_in[9];
    const float* W1 = (const float*)d_in[10];
    const float* b1 = (const float*)d_in[11];
    const float* W2 = (const float*)d_in[12];
    const float* b2 = (const float*)d_in[13];
    const float* eshift = (const float*)d_in[14];

    k0_sort<<<1, 1024, 0, stream>>>(type_map, sites_ws);
    k1_embed<<<B_ * N_, 256, 0, stream>>>(list_neigh, type_map, imagedr, c_param,
                                          scale, feat_ws, R_ws);
    k2_mlp<<<NT2, 256, 0, stream>>>(type_map, scale, W0, b0, W1, b1, W2, b2,
                                    eshift, feat_ws, feat_ws /*alias dfeat*/, out,
                                    sites_ws);
    k3a_prep<<<B_ * N_ / 2, 256, 0, stream>>>(type_map, c_param, feat_ws /*dfeat*/,
                                              R_ws, A_ws);
    k3_bwd<<<NG3, 256, 0, stream>>>(list_neigh, imagedr, A_ws, contrib_ws, vir_ws);
    k3_reduce<<<SL * B_ * 3, 256, 0, stream>>>(contrib_ws, partial_ws);
    k4_final<<<B_, 256, 0, stream>>>(vir_ws, partial_ws, out);
}